// Round 1
// baseline (1011.325 us; speedup 1.0000x reference)
//
#include <hip/hip_runtime.h>

#define Bq 32
#define Nq 300
#define Tq 12
#define Dq 64
#define Mq 16
#define BTq (Bq*Tq)      // 384
#define DDq (Dq*Dq)      // 4096
#define Fq (Dq*3)        // 192

__device__ __forceinline__ float gatef(float p) {
    float pc = fminf(fmaxf(p, -30.f), 30.f);
    float sig = 1.f / (1.f + __expf(-pc));
    float e2  = __expf(2.f * pc);
    float th  = (e2 - 1.f) / (e2 + 1.f);
    return sig * th;
}

// AAt[k*N+n] = (alpha1@alpha2)[n,k]; BBt likewise (stored transposed for coalesced reads)
__global__ void kprep_ab(const float* __restrict__ a1, const float* __restrict__ a2,
                         const float* __restrict__ b1, const float* __restrict__ b2,
                         float* __restrict__ AAt, float* __restrict__ BBt) {
    int e = blockIdx.x * 256 + threadIdx.x;
    if (e >= Nq * Nq) return;
    int k = e / Nq, n = e - k * Nq;
    float sa = 0.f, sb = 0.f;
    #pragma unroll
    for (int m = 0; m < Mq; ++m) {
        sa = fmaf(a1[n*Mq+m], a2[m*Nq+k], sa);
        sb = fmaf(b1[n*Mq+m], b2[m*Nq+k], sb);
    }
    AAt[e] = sa; BBt[e] = sb;
}

// W[n, k*64+d] = (trainW1@trainW2)[n, k*64+d]
__global__ void kprep_W(const float* __restrict__ w1, const float* __restrict__ w2,
                        float* __restrict__ W) {
    int e = blockIdx.x * 256 + threadIdx.x;
    if (e >= Nq * DDq) return;
    int n = e >> 12, i = e & (DDq - 1);
    float s = 0.f;
    #pragma unroll
    for (int m = 0; m < Mq; ++m) s = fmaf(w1[n*Mq+m], w2[m*DDq+i], s);
    W[e] = s;
}

// Xp[b,t,n,d] = X[b,d,n,t]
__global__ void ktr_x(const float* __restrict__ X, float* __restrict__ Xp) {
    int b = blockIdx.x / 10, chunk = blockIdx.x % 10;
    int n0 = chunk * 30;
    for (int i = threadIdx.x; i < 30 * Tq * Dq; i += 256) {
        int d = i & 63;
        int rem = i >> 6;            // 0..359
        int t = rem % Tq;
        int n = n0 + rem / Tq;
        Xp[((size_t)(b*Tq + t)*Nq + n)*Dq + d] = X[((size_t)(b*Dq + d)*Nq + n)*Tq + t];
    }
}

// Fused A-recompute + aggregation: Hout[bt,n,:] = sum_k A[bt,n,k] * Hb[bt,k,:]
// grid 768 = (bt, half of n); block 1024; dyn LDS 158000 B
__global__ void __launch_bounds__(1024) kagg(
    const float* __restrict__ te,    // [B,N,T,D]
    const float* __restrict__ adjW,  // [N,D]
    const float* __restrict__ adjB,  // [N]
    const float* __restrict__ AAt, const float* __restrict__ BBt,
    const float* __restrict__ Hb,    // [BT,N,D]
    float* __restrict__ Hout)        // [BT,N,D]
{
    extern __shared__ float smem[];
    float* sHb  = smem;              // 300*64 = 19200
    float* steT = smem + 19200;      // steT[d*150+nl], 9600
    float* sA   = smem + 28800;      // sA[kk*150+nl], 50*150 = 7500
    float* sWt  = smem + 36300;      // sWt[d*50+kk], 3200   -> total 39500 f = 158000 B

    const int bx   = blockIdx.x;
    const int bt   = bx >> 1;
    const int half = bx & 1;
    const int b = bt / Tq, t = bt - b * Tq;
    const int nbase = half * 150;
    const int tid = threadIdx.x;

    {   // stage full Hb tile [300][64], float4 coalesced
        int dq = tid & 15, r = tid >> 4;          // r in [0,64)
        for (int k = r; k < Nq; k += 64) {
            float4 v = *(const float4*)&Hb[((size_t)bt*Nq + k)*Dq + dq*4];
            *(float4*)&sHb[k*Dq + dq*4] = v;
        }
    }
    {   // stage te transposed: steT[d][nl]
        int d = tid & 63, r0 = tid >> 6;          // r0 in [0,16)
        for (int nl = r0; nl < 150; nl += 16)
            steT[d*150 + nl] = te[(((size_t)b*Nq + (nbase+nl))*Tq + t)*Dq + d];
    }
    __syncthreads();

    const int dq = tid & 15;
    const int nsub = tid >> 4;                    // 0..63
    float4 acc0 = make_float4(0.f,0.f,0.f,0.f);
    float4 acc1 = acc0, acc2 = acc0;

    for (int kt = 0; kt < 6; ++kt) {
        const int k0 = kt * 50;
        // stage adjW^T tile: sWt[d*50+kk] = adjW[(k0+kk)*64+d]
        for (int i = tid; i < Dq*50; i += 1024) {
            int d = i & 63, kk = i >> 6;
            sWt[d*50 + kk] = adjW[(k0+kk)*Dq + d];
        }
        __syncthreads();
        // A tile: 150 n x 25 kk-pairs
        for (int e = tid; e < 150*25; e += 1024) {
            int kkp = e / 150;
            int nl  = e - kkp*150;
            const float* pt = steT + nl;
            const float* pw = sWt + kkp*2;
            float s0 = 0.f, s1 = 0.f;
            #pragma unroll 8
            for (int d = 0; d < Dq; ++d) {
                float v = pt[d*150];
                float2 w = *(const float2*)&pw[d*50];
                s0 = fmaf(v, w.x, s0);
                s1 = fmaf(v, w.y, s1);
            }
            int kk0 = kkp*2;
            #pragma unroll
            for (int w = 0; w < 2; ++w) {
                int k = k0 + kk0 + w;
                float s = (w == 0) ? s0 : s1;
                float sv = __sinf(s + adjB[k]);
                size_t gi = (size_t)k*Nq + nbase + nl;
                float a = fmaf(AAt[gi], sv, BBt[gi]);
                sA[(kk0+w)*150 + nl] = fmaxf(a, 0.f);
            }
        }
        __syncthreads();
        // aggregation over this k-tile
        const bool has2 = (nsub < 22);
        #pragma unroll 2
        for (int kk = 0; kk < 50; ++kk) {
            const float4 hb = *(const float4*)&sHb[(k0+kk)*Dq + dq*4];
            const float* pa = sA + kk*150 + nsub;
            float a0 = pa[0], a1 = pa[64];
            acc0.x = fmaf(a0, hb.x, acc0.x); acc0.y = fmaf(a0, hb.y, acc0.y);
            acc0.z = fmaf(a0, hb.z, acc0.z); acc0.w = fmaf(a0, hb.w, acc0.w);
            acc1.x = fmaf(a1, hb.x, acc1.x); acc1.y = fmaf(a1, hb.y, acc1.y);
            acc1.z = fmaf(a1, hb.z, acc1.z); acc1.w = fmaf(a1, hb.w, acc1.w);
            if (has2) {
                float a2 = pa[128];
                acc2.x = fmaf(a2, hb.x, acc2.x); acc2.y = fmaf(a2, hb.y, acc2.y);
                acc2.z = fmaf(a2, hb.z, acc2.z); acc2.w = fmaf(a2, hb.w, acc2.w);
            }
        }
        __syncthreads();
    }
    size_t ob = ((size_t)bt*Nq + nbase + nsub)*Dq + dq*4;
    *(float4*)&Hout[ob] = acc0;
    *(float4*)&Hout[ob + (size_t)64*Dq] = acc1;
    if (nsub < 22) *(float4*)&Hout[ob + (size_t)128*Dq] = acc2;
}

// H1[bt,n,:] = gate(Xp[bt,n,:] + Hagg[bt,n,:] @ W[n])
__global__ void __launch_bounds__(256) kmm1(
    const float* __restrict__ Hagg, const float* __restrict__ Xp,
    const float* __restrict__ W, float* __restrict__ H1)
{
    __shared__ float sW[DDq];
    __shared__ float srow[Tq*Dq];
    int b = blockIdx.x / 25, chunk = blockIdx.x % 25;
    int n0 = chunk * 12;
    int tid = threadIdx.x;
    int dq = tid & 15, r = tid >> 4;
    for (int ni = 0; ni < 12; ++ni) {
        int n = n0 + ni;
        for (int i = tid; i < DDq; i += 256) sW[i] = W[(size_t)n*DDq + i];
        for (int i = tid; i < Tq*Dq; i += 256) {
            int rr = i >> 6, d = i & 63;
            srow[i] = Hagg[((size_t)(b*Tq + rr)*Nq + n)*Dq + d];
        }
        __syncthreads();
        if (r < Tq) {
            float4 acc = make_float4(0.f,0.f,0.f,0.f);
            #pragma unroll 8
            for (int k = 0; k < Dq; ++k) {
                float a = srow[r*Dq + k];
                float4 w = *(const float4*)&sW[k*Dq + dq*4];
                acc.x = fmaf(a, w.x, acc.x); acc.y = fmaf(a, w.y, acc.y);
                acc.z = fmaf(a, w.z, acc.z); acc.w = fmaf(a, w.w, acc.w);
            }
            size_t base = ((size_t)(b*Tq + r)*Nq + n)*Dq + dq*4;
            float4 xp = *(const float4*)&Xp[base];
            float4 h;
            h.x = gatef(xp.x + acc.x); h.y = gatef(xp.y + acc.y);
            h.z = gatef(xp.z + acc.z); h.w = gatef(xp.w + acc.w);
            *(float4*)&H1[base] = h;
        }
        __syncthreads();
    }
}

// H2 = gate(Xp + Hagg2@W[n]); out[b,d,n,t] = gcnB[d] + [Xp|H1|H2] @ gcnW[d,:]
__global__ void __launch_bounds__(256) kmm2g(
    const float* __restrict__ Hagg, const float* __restrict__ Xp,
    const float* __restrict__ H1, const float* __restrict__ W,
    const float* __restrict__ gcnW, const float* __restrict__ gcnB,
    float* __restrict__ out)
{
    extern __shared__ float sm2[];
    float* sGWt = sm2;               // [192][64], sGWt[f*64+d] = gcnW[d*192+f]: 12288
    float* sW   = sm2 + 12288;       // 4096
    float* sXp  = sm2 + 16384;       // 768
    float* sH1  = sm2 + 17152;       // 768
    float* sAg  = sm2 + 17920;       // 768
    float* sH2  = sm2 + 18688;       // 768  -> total 19456 f = 77824 B
    int b = blockIdx.x / 25, chunk = blockIdx.x % 25;
    int n0 = chunk * 12;
    int tid = threadIdx.x;
    for (int i = tid; i < Fq*Dq; i += 256) {
        int d = i & 63, f = i >> 6;
        sGWt[f*Dq + d] = gcnW[d*Fq + f];
    }
    int dq = tid & 15, r = tid >> 4;
    for (int ni = 0; ni < 12; ++ni) {
        int n = n0 + ni;
        for (int i = tid; i < DDq; i += 256) sW[i] = W[(size_t)n*DDq + i];
        for (int i = tid; i < Tq*Dq; i += 256) {
            int rr = i >> 6, d = i & 63;
            size_t base = ((size_t)(b*Tq + rr)*Nq + n)*Dq + d;
            sAg[i] = Hagg[base];
            sXp[i] = Xp[base];
            sH1[i] = H1[base];
        }
        __syncthreads();
        if (r < Tq) {
            float4 acc = make_float4(0.f,0.f,0.f,0.f);
            #pragma unroll 8
            for (int k = 0; k < Dq; ++k) {
                float a = sAg[r*Dq + k];
                float4 w = *(const float4*)&sW[k*Dq + dq*4];
                acc.x = fmaf(a, w.x, acc.x); acc.y = fmaf(a, w.y, acc.y);
                acc.z = fmaf(a, w.z, acc.z); acc.w = fmaf(a, w.w, acc.w);
            }
            float4 xp = *(const float4*)&sXp[r*Dq + dq*4];
            float4 h2;
            h2.x = gatef(xp.x + acc.x); h2.y = gatef(xp.y + acc.y);
            h2.z = gatef(xp.z + acc.z); h2.w = gatef(xp.w + acc.w);
            *(float4*)&sH2[r*Dq + dq*4] = h2;
        }
        __syncthreads();
        if (r < Tq) {
            float4 o = *(const float4*)&gcnB[dq*4];
            #pragma unroll 4
            for (int f = 0; f < Dq; ++f) {
                float hv = sXp[r*Dq + f];
                float4 w = *(const float4*)&sGWt[f*Dq + dq*4];
                o.x = fmaf(hv, w.x, o.x); o.y = fmaf(hv, w.y, o.y);
                o.z = fmaf(hv, w.z, o.z); o.w = fmaf(hv, w.w, o.w);
            }
            #pragma unroll 4
            for (int f = 0; f < Dq; ++f) {
                float hv = sH1[r*Dq + f];
                float4 w = *(const float4*)&sGWt[(Dq+f)*Dq + dq*4];
                o.x = fmaf(hv, w.x, o.x); o.y = fmaf(hv, w.y, o.y);
                o.z = fmaf(hv, w.z, o.z); o.w = fmaf(hv, w.w, o.w);
            }
            #pragma unroll 4
            for (int f = 0; f < Dq; ++f) {
                float hv = sH2[r*Dq + f];
                float4 w = *(const float4*)&sGWt[(2*Dq+f)*Dq + dq*4];
                o.x = fmaf(hv, w.x, o.x); o.y = fmaf(hv, w.y, o.y);
                o.z = fmaf(hv, w.z, o.z); o.w = fmaf(hv, w.w, o.w);
            }
            size_t ob = ((size_t)(b*Dq + dq*4)*Nq + n)*Tq + r;
            out[ob]                    = o.x;
            out[ob + (size_t)Nq*Tq]    = o.y;
            out[ob + (size_t)2*Nq*Tq]  = o.z;
            out[ob + (size_t)3*Nq*Tq]  = o.w;
        }
        __syncthreads();
    }
}

extern "C" void kernel_launch(void* const* d_in, const int* in_sizes, int n_in,
                              void* d_out, int out_size, void* d_ws, size_t ws_size,
                              hipStream_t stream) {
    (void)in_sizes; (void)n_in; (void)out_size; (void)ws_size;
    const float* X    = (const float*)d_in[0];
    const float* te   = (const float*)d_in[1];
    const float* adjW = (const float*)d_in[2];
    const float* adjB = (const float*)d_in[3];
    const float* w1   = (const float*)d_in[4];
    const float* w2   = (const float*)d_in[5];
    const float* a1   = (const float*)d_in[6];
    const float* a2   = (const float*)d_in[7];
    const float* b1   = (const float*)d_in[8];
    const float* b2   = (const float*)d_in[9];
    const float* gW   = (const float*)d_in[10];
    const float* gB   = (const float*)d_in[11];
    float* out = (float*)d_out;

    float* ws   = (float*)d_ws;
    float* AAt  = ws;                     // 90000
    float* BBt  = AAt + 90000;            // 90000
    float* W    = BBt + 90000;            // 1228800
    float* Xp   = W   + 1228800;          // 7372800
    float* Hagg = Xp  + 7372800;          // 7372800
    float* H1   = Hagg + 7372800;         // 7372800  => total 94.1 MB

    hipLaunchKernelGGL(kprep_ab, dim3(352),  dim3(256), 0, stream, a1, a2, b1, b2, AAt, BBt);
    hipLaunchKernelGGL(kprep_W,  dim3(4800), dim3(256), 0, stream, w1, w2, W);
    hipLaunchKernelGGL(ktr_x,    dim3(320),  dim3(256), 0, stream, X, Xp);
    // hop 1
    hipLaunchKernelGGL(kagg, dim3(768), dim3(1024), 158000, stream, te, adjW, adjB, AAt, BBt, Xp, Hagg);
    hipLaunchKernelGGL(kmm1, dim3(800), dim3(256), 0, stream, Hagg, Xp, W, H1);
    // hop 2
    hipLaunchKernelGGL(kagg, dim3(768), dim3(1024), 158000, stream, te, adjW, adjB, AAt, BBt, H1, Hagg);
    hipLaunchKernelGGL(kmm2g, dim3(800), dim3(256), 77824, stream, Hagg, Xp, H1, W, gW, gB, out);
}

// Round 2
// 893.331 us; speedup vs baseline: 1.1321x; 1.1321x over previous
//
#include <hip/hip_runtime.h>

#define Nq 300
#define Tq 12
#define Dq 64
#define Mq 16
#define DDq (Dq*Dq)      // 4096
#define Fq (Dq*3)        // 192

typedef short bf8_t __attribute__((ext_vector_type(8)));
typedef float f4_t  __attribute__((ext_vector_type(4)));

__device__ __forceinline__ unsigned short f2bf(float f) {
    unsigned u = __float_as_uint(f);
    u = (u + 0x7FFFu + ((u >> 16) & 1u)) >> 16;
    return (unsigned short)u;
}

__device__ __forceinline__ float gatef(float p) {
    float pc = fminf(fmaxf(p, -30.f), 30.f);
    float sig = 1.f / (1.f + __expf(-pc));
    float e2  = __expf(2.f * pc);
    float th  = (e2 - 1.f) / (e2 + 1.f);
    return sig * th;
}

// AA[n*300+k] = (alpha1@alpha2)[n,k]; BB likewise ([n][k] layout, k contiguous)
__global__ void kprep_ab(const float* __restrict__ a1, const float* __restrict__ a2,
                         const float* __restrict__ b1, const float* __restrict__ b2,
                         float* __restrict__ AA, float* __restrict__ BB) {
    int e = blockIdx.x * 256 + threadIdx.x;
    if (e >= Nq * Nq) return;
    int n = e / Nq, k = e - n * Nq;
    float sa = 0.f, sb = 0.f;
    #pragma unroll
    for (int m = 0; m < Mq; ++m) {
        sa = fmaf(a1[n*Mq+m], a2[m*Nq+k], sa);
        sb = fmaf(b1[n*Mq+m], b2[m*Nq+k], sb);
    }
    AA[e] = sa; BB[e] = sb;
}

// W[n, k*64+d] = (trainW1@trainW2)[n, k*64+d]
__global__ void kprep_W(const float* __restrict__ w1, const float* __restrict__ w2,
                        float* __restrict__ W) {
    int e = blockIdx.x * 256 + threadIdx.x;
    if (e >= Nq * DDq) return;
    int n = e >> 12, i = e & (DDq - 1);
    float s = 0.f;
    #pragma unroll
    for (int m = 0; m < Mq; ++m) s = fmaf(w1[n*Mq+m], w2[m*DDq+i], s);
    W[e] = s;
}

// Tiled transpose Xp[b,t,n,d] = X[b,d,n,t]; both sides coalesced via LDS.
__global__ void __launch_bounds__(256) ktr_x(const float* __restrict__ X, float* __restrict__ Xp) {
    __shared__ float sX[64 * 193];         // [d][nl*12+t], stride 193 (conflict-free)
    int b = blockIdx.x / 19, tile = blockIdx.x % 19;
    int n0 = tile * 16;
    int tid = threadIdx.x;
    for (int i = tid; i < 64 * 192; i += 256) {
        int d = i / 192, j = i - d * 192;  // j = nl*12 + t
        float v = (n0 * 12 + j < 3600) ? X[(size_t)(b*64 + d)*3600 + n0*12 + j] : 0.f;
        sX[d * 193 + j] = v;
    }
    __syncthreads();
    for (int wo = tid; wo < 64 * 192; wo += 256) {
        int d = wo & 63, rl = wo >> 6;     // rl = nl*12 + t
        int nl = rl / 12, t = rl - nl * 12;
        int n = n0 + nl;
        if (n < Nq)
            Xp[((size_t)(b*Tq + t)*Nq + n)*Dq + d] = sX[d * 193 + rl];
    }
}

// Fused A-recompute (MFMA) + aggregation (MFMA), flash-style.
// grid 768 = (bt, n-half of 160 rows); block 256 (4 waves); dyn LDS 134144 B.
// Hout[bt,n,:] = relu(AA.*sin(te@adjW^T + adjB) + BB) @ Hb[bt]
__global__ void __launch_bounds__(256) kfuse(
    const float* __restrict__ te,    // [B,N,T,D]
    const float* __restrict__ adjW,  // [N,D]
    const float* __restrict__ adjB,  // [N]
    const float* __restrict__ AA, const float* __restrict__ BB,  // [n][k]
    const float* __restrict__ Hb,    // [BT,N,D]
    float* __restrict__ Hout)        // [BT,N,D]
{
    extern __shared__ unsigned short us[];
    unsigned short* sTe  = us;            // [160][72] bf16
    unsigned short* sAdj = us + 11520;    // [320][72]
    unsigned short* sVt  = us + 34560;    // [64][328]  (Hb transposed)
    unsigned short* sPl  = us + 55552;    // [160][72]  (P chunk, A-layout)

    const int bx = blockIdx.x;
    const int bt = bx >> 1, hf = bx & 1;
    const int b = bt / Tq, t = bt - b * Tq;
    const int nbase = hf * 160;
    const int tid = threadIdx.x;
    const int w = tid >> 6, lane = tid & 63;
    const int quad = lane >> 4, l16 = lane & 15;

    for (int i = tid; i < 320 * 64; i += 256) {       // adjW rows (zero-pad k>=300)
        int d = i & 63, k = i >> 6;
        float v = (k < Nq) ? adjW[k*Dq + d] : 0.f;
        sAdj[k*72 + d] = f2bf(v);
    }
    for (int i = tid; i < 160 * 64; i += 256) {       // te rows nbase..nbase+159
        int d = i & 63, r = i >> 6;
        int n = nbase + r;
        float v = (n < Nq) ? te[(((size_t)b*Nq + n)*Tq + t)*Dq + d] : 0.f;
        sTe[r*72 + d] = f2bf(v);
    }
    for (int i = tid; i < 320 * 64; i += 256) {       // Hb transposed [d][k]
        int d = i & 63, k = i >> 6;
        float v = (k < Nq) ? Hb[((size_t)bt*Nq + k)*Dq + d] : 0.f;
        sVt[d*328 + k] = f2bf(v);
    }
    __syncthreads();

    f4_t accO[10];
    #pragma unroll
    for (int rt = 0; rt < 10; ++rt) accO[rt] = (f4_t){0.f, 0.f, 0.f, 0.f};

    for (int c = 0; c < 5; ++c) {
        const int cbase = c * 64;
        // ---- GEMM1: P[n, k-chunk] = te @ adjW^T ; wave w owns k-tile w
        const int ktb = cbase + w*16;
        bf8_t kb0 = *(const bf8_t*)&sAdj[(ktb + l16)*72 + quad*8];
        bf8_t kb1 = *(const bf8_t*)&sAdj[(ktb + l16)*72 + 32 + quad*8];
        const int kglob = ktb + l16;
        const int kc = (kglob < Nq) ? kglob : 0;
        const float bias = adjB[kc];
        #pragma unroll
        for (int rt = 0; rt < 10; ++rt) {
            bf8_t a0 = *(const bf8_t*)&sTe[(rt*16 + l16)*72 + quad*8];
            bf8_t a1 = *(const bf8_t*)&sTe[(rt*16 + l16)*72 + 32 + quad*8];
            f4_t p = {0.f, 0.f, 0.f, 0.f};
            p = __builtin_amdgcn_mfma_f32_16x16x32_bf16(a0, kb0, p, 0, 0, 0);
            p = __builtin_amdgcn_mfma_f32_16x16x32_bf16(a1, kb1, p, 0, 0, 0);
            #pragma unroll
            for (int reg = 0; reg < 4; ++reg) {
                int nl = rt*16 + quad*4 + reg;        // P row (C-layout: row=quad*4+reg)
                int ng = nbase + nl;
                int ncp = (ng < Nq) ? ng : Nq - 1;
                float sv = __sinf(p[reg] + bias);
                float a = fmaf(AA[ncp*Nq + kc], sv, BB[ncp*Nq + kc]);
                a = fmaxf(a, 0.f);
                if (kglob >= Nq) a = 0.f;             // zero padded k columns
                sPl[nl*72 + w*16 + l16] = f2bf(a);    // store in A-operand layout
            }
        }
        __syncthreads();
        // ---- GEMM2: O += P @ Hb[chunk] ; wave w owns d-tile w
        bf8_t v0 = *(const bf8_t*)&sVt[(w*16 + l16)*328 + cbase + quad*8];
        bf8_t v1 = *(const bf8_t*)&sVt[(w*16 + l16)*328 + cbase + 32 + quad*8];
        #pragma unroll
        for (int rt = 0; rt < 10; ++rt) {
            bf8_t a0 = *(const bf8_t*)&sPl[(rt*16 + l16)*72 + quad*8];
            bf8_t a1 = *(const bf8_t*)&sPl[(rt*16 + l16)*72 + 32 + quad*8];
            accO[rt] = __builtin_amdgcn_mfma_f32_16x16x32_bf16(a0, v0, accO[rt], 0, 0, 0);
            accO[rt] = __builtin_amdgcn_mfma_f32_16x16x32_bf16(a1, v1, accO[rt], 0, 0, 0);
        }
        __syncthreads();
    }
    const int d = w*16 + l16;
    #pragma unroll
    for (int rt = 0; rt < 10; ++rt) {
        #pragma unroll
        for (int reg = 0; reg < 4; ++reg) {
            int ng = nbase + rt*16 + quad*4 + reg;
            if (ng < Nq) Hout[((size_t)bt*Nq + ng)*Dq + d] = accO[rt][reg];
        }
    }
}

// Per-node matmul + gate: Hout[bt,n,:] = gate(Xp + Hagg[bt,n,:] @ W[n]).
// Block per (n, bt-quarter of 96). Safe in-place (Hout may alias Hagg).
__global__ void __launch_bounds__(256) kmm(
    const float* __restrict__ Hagg, const float* __restrict__ Xp,
    const float* __restrict__ W, float* __restrict__ Hout)
{
    __shared__ float sW[DDq];            // 16 KB
    __shared__ float sRows[16 * 68];     // padded stride 68
    const int n = blockIdx.x >> 2, qtr = blockIdx.x & 3;
    const int tid = threadIdx.x;
    const int rg = tid >> 4, dq = tid & 15;
    for (int i = tid; i < DDq; i += 256) sW[i] = W[(size_t)n*DDq + i];
    for (int bat = 0; bat < 6; ++bat) {
        int bt0 = qtr * 96 + bat * 16;
        __syncthreads();
        {   // stage 16 rows of Hagg
            int row = tid >> 4, q = tid & 15;
            *(float4*)&sRows[row*68 + q*4] =
                *(const float4*)&Hagg[((size_t)(bt0 + row)*Nq + n)*Dq + q*4];
        }
        __syncthreads();
        float4 acc = make_float4(0.f, 0.f, 0.f, 0.f);
        #pragma unroll 4
        for (int k = 0; k < Dq; k += 4) {
            float4 a4 = *(const float4*)&sRows[rg*68 + k];
            #pragma unroll
            for (int e = 0; e < 4; ++e) {
                float a = (e == 0) ? a4.x : (e == 1) ? a4.y : (e == 2) ? a4.z : a4.w;
                float4 w4 = *(const float4*)&sW[(k + e)*Dq + dq*4];
                acc.x = fmaf(a, w4.x, acc.x); acc.y = fmaf(a, w4.y, acc.y);
                acc.z = fmaf(a, w4.z, acc.z); acc.w = fmaf(a, w4.w, acc.w);
            }
        }
        size_t base = ((size_t)(bt0 + rg)*Nq + n)*Dq + dq*4;
        float4 xp = *(const float4*)&Xp[base];
        float4 h;
        h.x = gatef(xp.x + acc.x); h.y = gatef(xp.y + acc.y);
        h.z = gatef(xp.z + acc.z); h.w = gatef(xp.w + acc.w);
        *(float4*)&Hout[base] = h;
    }
}

// GCN epilogue: out[b,d,n,t] = gcnB[d] + [Xp|H1|H2]@gcnW[d,:], coalesced store via LDS tile.
// Block per (b, n-tile of 12) = 800 blocks; dyn LDS 99904 B.
__global__ void __launch_bounds__(256) kgcn(
    const float* __restrict__ Xp, const float* __restrict__ H1,
    const float* __restrict__ H2, const float* __restrict__ gcnW,
    const float* __restrict__ gcnB, float* __restrict__ out)
{
    extern __shared__ float sm[];
    float* sGWt = sm;                  // [192][68] : sGWt[f*68+d] = gcnW[d*192+f]
    float* sRX  = sm + 13056;          // [12][68]
    float* sR1  = sm + 13872;
    float* sR2  = sm + 14688;
    float* sOut = sm + 15504;          // [64][148]
    const int b = blockIdx.x / 25, chunk = blockIdx.x % 25;
    const int n0 = chunk * 12;
    const int tid = threadIdx.x;
    const int r = tid >> 4, dq = tid & 15;
    for (int i = tid; i < Fq * Dq; i += 256) {
        int d = i / Fq, f = i - d * Fq;
        sGWt[f*68 + d] = gcnW[i];
    }
    const float* bufs[3] = {Xp, H1, H2};
    for (int ni = 0; ni < 12; ++ni) {
        int n = n0 + ni;
        __syncthreads();
        for (int i = tid; i < 3 * Tq * Dq; i += 256) {
            int which = i / 768, j = i - which * 768;
            int tt = j >> 6, d = j & 63;
            float v = bufs[which][((size_t)(b*Tq + tt)*Nq + n)*Dq + d];
            float* dst = (which == 0) ? sRX : (which == 1) ? sR1 : sR2;
            dst[tt*68 + d] = v;
        }
        __syncthreads();
        if (r < Tq) {
            float4 o = *(const float4*)&gcnB[dq*4];
            #pragma unroll
            for (int buf = 0; buf < 3; ++buf) {
                const float* sR = (buf == 0) ? sRX : (buf == 1) ? sR1 : sR2;
                const int fo = buf * Dq;
                #pragma unroll 4
                for (int f = 0; f < Dq; f += 4) {
                    float4 a4 = *(const float4*)&sR[r*68 + f];
                    #pragma unroll
                    for (int e = 0; e < 4; ++e) {
                        float a = (e == 0) ? a4.x : (e == 1) ? a4.y : (e == 2) ? a4.z : a4.w;
                        float4 w4 = *(const float4*)&sGWt[(fo + f + e)*68 + dq*4];
                        o.x = fmaf(a, w4.x, o.x); o.y = fmaf(a, w4.y, o.y);
                        o.z = fmaf(a, w4.z, o.z); o.w = fmaf(a, w4.w, o.w);
                    }
                }
            }
            sOut[(dq*4 + 0)*148 + ni*12 + r] = o.x;
            sOut[(dq*4 + 1)*148 + ni*12 + r] = o.y;
            sOut[(dq*4 + 2)*148 + ni*12 + r] = o.z;
            sOut[(dq*4 + 3)*148 + ni*12 + r] = o.w;
        }
    }
    __syncthreads();
    for (int i = tid; i < 64 * 36; i += 256) {      // 2304 float4
        int d = i / 36, q = i - d * 36;
        float4 v = *(const float4*)&sOut[d*148 + q*4];
        *(float4*)&out[(size_t)(b*Dq + d)*3600 + n0*12 + q*4] = v;
    }
}

extern "C" void kernel_launch(void* const* d_in, const int* in_sizes, int n_in,
                              void* d_out, int out_size, void* d_ws, size_t ws_size,
                              hipStream_t stream) {
    (void)in_sizes; (void)n_in; (void)out_size; (void)ws_size;
    const float* X    = (const float*)d_in[0];
    const float* te   = (const float*)d_in[1];
    const float* adjW = (const float*)d_in[2];
    const float* adjB = (const float*)d_in[3];
    const float* w1   = (const float*)d_in[4];
    const float* w2   = (const float*)d_in[5];
    const float* a1   = (const float*)d_in[6];
    const float* a2   = (const float*)d_in[7];
    const float* b1   = (const float*)d_in[8];
    const float* b2   = (const float*)d_in[9];
    const float* gW   = (const float*)d_in[10];
    const float* gB   = (const float*)d_in[11];
    float* out = (float*)d_out;

    float* ws   = (float*)d_ws;
    float* AA   = ws;                     // 90000
    float* BB   = AA + 90000;             // 90000
    float* W    = BB + 90000;             // 1228800
    float* Xp   = W   + 1228800;          // 7372800
    float* Hagg = Xp  + 7372800;          // 7372800
    float* H1   = Hagg + 7372800;         // 7372800  => 93.9 MB total

    hipLaunchKernelGGL(kprep_ab, dim3(352),  dim3(256), 0, stream, a1, a2, b1, b2, AA, BB);
    hipLaunchKernelGGL(kprep_W,  dim3(4800), dim3(256), 0, stream, w1, w2, W);
    hipLaunchKernelGGL(ktr_x,    dim3(608),  dim3(256), 0, stream, X, Xp);
    // hop 1
    hipLaunchKernelGGL(kfuse, dim3(768), dim3(256), 134144, stream, te, adjW, adjB, AA, BB, Xp, Hagg);
    hipLaunchKernelGGL(kmm,   dim3(1200), dim3(256), 0, stream, Hagg, Xp, W, H1);
    // hop 2
    hipLaunchKernelGGL(kfuse, dim3(768), dim3(256), 134144, stream, te, adjW, adjB, AA, BB, H1, Hagg);
    hipLaunchKernelGGL(kmm,   dim3(1200), dim3(256), 0, stream, Hagg, Xp, W, Hagg); // in-place gate
    // gcn epilogue
    hipLaunchKernelGGL(kgcn,  dim3(800), dim3(256), 99904, stream, Xp, H1, Hagg, gW, gB, out);
}

// Round 3
// 651.354 us; speedup vs baseline: 1.5527x; 1.3715x over previous
//
#include <hip/hip_runtime.h>

#define Nq 300
#define Tq 12
#define Dq 64
#define Mq 16
#define DDq (Dq*Dq)      // 4096
#define Fq (Dq*3)        // 192

typedef short bf8_t __attribute__((ext_vector_type(8)));
typedef float f4_t  __attribute__((ext_vector_type(4)));

__device__ __forceinline__ unsigned short f2bf(float f) {
    unsigned u = __float_as_uint(f);
    u = (u + 0x7FFFu + ((u >> 16) & 1u)) >> 16;
    return (unsigned short)u;
}

__device__ __forceinline__ float4 ld4(const float* p) { return *(const float4*)p; }

__device__ __forceinline__ bf8_t pack8(float4 a, float4 b) {
    bf8_t r;
    r[0] = (short)f2bf(a.x); r[1] = (short)f2bf(a.y);
    r[2] = (short)f2bf(a.z); r[3] = (short)f2bf(a.w);
    r[4] = (short)f2bf(b.x); r[5] = (short)f2bf(b.y);
    r[6] = (short)f2bf(b.z); r[7] = (short)f2bf(b.w);
    return r;
}

__device__ __forceinline__ float gatef(float p) {
    float pc = fminf(fmaxf(p, -30.f), 30.f);
    float sig = 1.f / (1.f + __expf(-pc));
    float e2  = __expf(2.f * pc);
    float th  = (e2 - 1.f) / (e2 + 1.f);
    return sig * th;
}

// AB[(n*300+k)*2] = (alpha1@alpha2)[n,k]; +1 = (beta1@beta2)[n,k]  (interleaved)
__global__ void kprep_ab(const float* __restrict__ a1, const float* __restrict__ a2,
                         const float* __restrict__ b1, const float* __restrict__ b2,
                         float* __restrict__ AB) {
    int e = blockIdx.x * 256 + threadIdx.x;
    if (e >= Nq * Nq) return;
    int n = e / Nq, k = e - n * Nq;
    float sa = 0.f, sb = 0.f;
    #pragma unroll
    for (int m = 0; m < Mq; ++m) {
        sa = fmaf(a1[n*Mq+m], a2[m*Nq+k], sa);
        sb = fmaf(b1[n*Mq+m], b2[m*Nq+k], sb);
    }
    AB[e*2] = sa; AB[e*2+1] = sb;
}

// Wt bf16 [n][d][k] = (trainW1@trainW2)[n, k*64+d]  (transposed for MFMA B-frags)
__global__ void kprep_W(const float* __restrict__ w1, const float* __restrict__ w2,
                        unsigned short* __restrict__ Wt) {
    int e = blockIdx.x * 256 + threadIdx.x;
    if (e >= Nq * DDq) return;
    int n = e >> 12, i = e & (DDq - 1);
    int d = i >> 6, k = i & 63;
    float s = 0.f;
    #pragma unroll
    for (int m = 0; m < Mq; ++m) s = fmaf(w1[n*Mq+m], w2[m*DDq + k*Dq + d], s);
    Wt[e] = f2bf(s);
}

// Tiled transpose Xp[b,t,n,d] = X[b,d,n,t]; both sides coalesced via LDS.
__global__ void __launch_bounds__(256) ktr_x(const float* __restrict__ X, float* __restrict__ Xp) {
    __shared__ float sX[64 * 193];
    int b = blockIdx.x / 19, tile = blockIdx.x % 19;
    int n0 = tile * 16;
    int tid = threadIdx.x;
    for (int i = tid; i < 64 * 192; i += 256) {
        int d = i / 192, j = i - d * 192;
        float v = (n0 * 12 + j < 3600) ? X[(size_t)(b*64 + d)*3600 + n0*12 + j] : 0.f;
        sX[d * 193 + j] = v;
    }
    __syncthreads();
    for (int wo = tid; wo < 64 * 192; wo += 256) {
        int d = wo & 63, rl = wo >> 6;
        int nl = rl / 12, t = rl - nl * 12;
        int n = n0 + nl;
        if (n < Nq)
            Xp[((size_t)(b*Tq + t)*Nq + n)*Dq + d] = sX[d * 193 + rl];
    }
}

// Fused A-recompute + aggregation, direct-load MFMA. grid 768 = (bt, n-half of 160).
// Only LDS: P round-trip [160][72] bf16 = 23040 B.
__global__ void __launch_bounds__(256) kfuse(
    const float* __restrict__ te,    // [B,N,T,D]
    const float* __restrict__ adjW,  // [N,D]
    const float* __restrict__ adjB,  // [N]
    const float* __restrict__ AB,    // [n][k][2]
    const float* __restrict__ Hb,    // [BT,N,D]
    float* __restrict__ Hout)        // [BT,N,D]
{
    __shared__ unsigned short sPl[160 * 72];
    const int bt = blockIdx.x >> 1, hf = blockIdx.x & 1;
    const int b = bt / Tq, t = bt - b * Tq;
    const int nbase = hf * 160;
    const int tid = threadIdx.x;
    const int w = tid >> 6, lane = tid & 63, quad = lane >> 4, l16 = lane & 15;
    const int dcol = w*16 + l16;

    f4_t accO[10];
    #pragma unroll
    for (int rt = 0; rt < 10; ++rt) accO[rt] = (f4_t){0.f, 0.f, 0.f, 0.f};

    for (int c = 0; c < 5; ++c) {
        const int cbase = c * 64;
        const int kglob = cbase + w*16 + l16;       // P column this lane produces
        const int kc = (kglob < Nq) ? kglob : Nq - 1;
        const float bias = adjB[kc];
        const float* awr = adjW + (size_t)kc * Dq;
        bf8_t kb0 = pack8(ld4(awr + quad*8),      ld4(awr + quad*8 + 4));
        bf8_t kb1 = pack8(ld4(awr + 32 + quad*8), ld4(awr + 36 + quad*8));
        #pragma unroll 2
        for (int rt = 0; rt < 10; ++rt) {
            int nr = nbase + rt*16 + l16; if (nr > Nq-1) nr = Nq-1;
            const float* ter = te + (((size_t)b*Nq + nr)*Tq + t)*Dq;
            bf8_t a0 = pack8(ld4(ter + quad*8),      ld4(ter + quad*8 + 4));
            bf8_t a1 = pack8(ld4(ter + 32 + quad*8), ld4(ter + 36 + quad*8));
            f4_t p = {0.f, 0.f, 0.f, 0.f};
            p = __builtin_amdgcn_mfma_f32_16x16x32_bf16(a0, kb0, p, 0, 0, 0);
            p = __builtin_amdgcn_mfma_f32_16x16x32_bf16(a1, kb1, p, 0, 0, 0);
            #pragma unroll
            for (int reg = 0; reg < 4; ++reg) {
                int nl = rt*16 + quad*4 + reg;
                int ng = nbase + nl;
                int ncp = (ng < Nq) ? ng : Nq - 1;
                float2 ab = *(const float2*)&AB[((size_t)ncp*Nq + kc)*2];
                float sv = __sinf(p[reg] + bias);
                float a = fmaf(ab.x, sv, ab.y);
                a = fmaxf(a, 0.f);
                if (kglob >= Nq) a = 0.f;
                sPl[nl*72 + w*16 + l16] = f2bf(a);
            }
        }
        __syncthreads();
        bf8_t v0, v1;
        #pragma unroll
        for (int j = 0; j < 8; ++j) {
            int k0 = cbase + quad*8 + j;
            v0[j] = (k0 < Nq) ? (short)f2bf(Hb[((size_t)bt*Nq + k0)*Dq + dcol]) : (short)0;
            int k1 = k0 + 32;
            v1[j] = (k1 < Nq) ? (short)f2bf(Hb[((size_t)bt*Nq + k1)*Dq + dcol]) : (short)0;
        }
        #pragma unroll
        for (int rt = 0; rt < 10; ++rt) {
            bf8_t p0 = *(const bf8_t*)&sPl[(rt*16 + l16)*72 + quad*8];
            bf8_t p1 = *(const bf8_t*)&sPl[(rt*16 + l16)*72 + 32 + quad*8];
            accO[rt] = __builtin_amdgcn_mfma_f32_16x16x32_bf16(p0, v0, accO[rt], 0, 0, 0);
            accO[rt] = __builtin_amdgcn_mfma_f32_16x16x32_bf16(p1, v1, accO[rt], 0, 0, 0);
        }
        __syncthreads();
    }
    #pragma unroll
    for (int rt = 0; rt < 10; ++rt) {
        #pragma unroll
        for (int reg = 0; reg < 4; ++reg) {
            int ng = nbase + rt*16 + quad*4 + reg;
            if (ng < Nq) Hout[((size_t)bt*Nq + ng)*Dq + dcol] = accO[rt][reg];
        }
    }
}

// Per-node matmul + gate, direct-load MFMA, zero LDS. grid 600 = (n, bt-half of 192).
// In-place safe via barrier (all A loads complete before any store).
__global__ void __launch_bounds__(256) kmm(
    const float* __restrict__ Hagg, const float* __restrict__ Xp,
    const unsigned short* __restrict__ Wt, float* __restrict__ Hout)
{
    const int n = blockIdx.x >> 1, hf = blockIdx.x & 1;
    const int bt0 = hf * 192;
    const int tid = threadIdx.x;
    const int w = tid >> 6, lane = tid & 63, quad = lane >> 4, l16 = lane & 15;
    const int dcol = w*16 + l16;
    const unsigned short* wn = Wt + (size_t)n * DDq;
    bf8_t v0 = *(const bf8_t*)&wn[dcol*Dq + quad*8];
    bf8_t v1 = *(const bf8_t*)&wn[dcol*Dq + 32 + quad*8];
    f4_t acc[12];
    #pragma unroll
    for (int rt = 0; rt < 12; ++rt) acc[rt] = (f4_t){0.f, 0.f, 0.f, 0.f};
    #pragma unroll 3
    for (int rt = 0; rt < 12; ++rt) {
        int r = bt0 + rt*16 + l16;
        const float* row = &Hagg[((size_t)r*Nq + n)*Dq];
        bf8_t a0 = pack8(ld4(row + quad*8),      ld4(row + quad*8 + 4));
        bf8_t a1 = pack8(ld4(row + 32 + quad*8), ld4(row + 36 + quad*8));
        acc[rt] = __builtin_amdgcn_mfma_f32_16x16x32_bf16(a0, v0, acc[rt], 0, 0, 0);
        acc[rt] = __builtin_amdgcn_mfma_f32_16x16x32_bf16(a1, v1, acc[rt], 0, 0, 0);
    }
    __syncthreads();
    #pragma unroll
    for (int rt = 0; rt < 12; ++rt) {
        #pragma unroll
        for (int reg = 0; reg < 4; ++reg) {
            int r = bt0 + rt*16 + quad*4 + reg;
            size_t idx = ((size_t)r*Nq + n)*Dq + dcol;
            Hout[idx] = gatef(Xp[idx] + acc[rt][reg]);
        }
    }
}

// GCN epilogue as pure-register MFMA GEMM: C[192 rows x 64 d], K=192.
// grid 608 = (b, n-tile of 16); rows r = nl*12 + t; direct float4 stores to out.
__global__ void __launch_bounds__(256) kgcn(
    const float* __restrict__ Xp, const float* __restrict__ H1,
    const float* __restrict__ H2, const float* __restrict__ gcnW,
    const float* __restrict__ gcnB, float* __restrict__ out)
{
    const int b = blockIdx.x / 19, tile = blockIdx.x % 19;
    const int n0 = tile * 16;
    const int rows = (tile == 18) ? 144 : 192;
    const int tid = threadIdx.x;
    const int w = tid >> 6, lane = tid & 63, quad = lane >> 4, l16 = lane & 15;
    const int dcol = w*16 + l16;
    const float bias = gcnB[dcol];
    f4_t acc[12];
    #pragma unroll
    for (int rt = 0; rt < 12; ++rt) acc[rt] = (f4_t){0.f, 0.f, 0.f, 0.f};
    const float* bufs[3] = {Xp, H1, H2};
    #pragma unroll
    for (int c = 0; c < 3; ++c) {
        const float* buf = bufs[c];
        const float* gwr = gcnW + (size_t)dcol*Fq + c*Dq;
        bf8_t v0 = pack8(ld4(gwr + quad*8),      ld4(gwr + quad*8 + 4));
        bf8_t v1 = pack8(ld4(gwr + 32 + quad*8), ld4(gwr + 36 + quad*8));
        #pragma unroll 3
        for (int rt = 0; rt < 12; ++rt) {
            int r = rt*16 + l16;
            int nl = r / 12, t = r - nl*12;
            int n = n0 + nl; if (n > Nq-1) n = Nq-1;
            const float* row = &buf[((size_t)(b*Tq + t)*Nq + n)*Dq];
            bf8_t a0 = pack8(ld4(row + quad*8),      ld4(row + quad*8 + 4));
            bf8_t a1 = pack8(ld4(row + 32 + quad*8), ld4(row + 36 + quad*8));
            acc[rt] = __builtin_amdgcn_mfma_f32_16x16x32_bf16(a0, v0, acc[rt], 0, 0, 0);
            acc[rt] = __builtin_amdgcn_mfma_f32_16x16x32_bf16(a1, v1, acc[rt], 0, 0, 0);
        }
    }
    float* outd = out + (size_t)(b*Dq + dcol)*3600 + n0*12;
    #pragma unroll
    for (int rt = 0; rt < 12; ++rt) {
        if (rt*16 >= rows) break;
        int r0 = rt*16 + quad*4;
        float4 o = make_float4(acc[rt][0] + bias, acc[rt][1] + bias,
                               acc[rt][2] + bias, acc[rt][3] + bias);
        *(float4*)&outd[r0] = o;
    }
}

extern "C" void kernel_launch(void* const* d_in, const int* in_sizes, int n_in,
                              void* d_out, int out_size, void* d_ws, size_t ws_size,
                              hipStream_t stream) {
    (void)in_sizes; (void)n_in; (void)out_size; (void)ws_size;
    const float* X    = (const float*)d_in[0];
    const float* te   = (const float*)d_in[1];
    const float* adjW = (const float*)d_in[2];
    const float* adjB = (const float*)d_in[3];
    const float* w1   = (const float*)d_in[4];
    const float* w2   = (const float*)d_in[5];
    const float* a1   = (const float*)d_in[6];
    const float* a2   = (const float*)d_in[7];
    const float* b1   = (const float*)d_in[8];
    const float* b2   = (const float*)d_in[9];
    const float* gW   = (const float*)d_in[10];
    const float* gB   = (const float*)d_in[11];
    float* out = (float*)d_out;

    float* ws = (float*)d_ws;
    float*          AB   = ws;                               // 180000 f
    unsigned short* Wt   = (unsigned short*)(ws + 180000);   // 1228800 u16 = 614400 f
    float*          Xp   = ws + 794400;                      // 7372800 f
    float*          Hagg = Xp + 7372800;
    float*          H1   = Hagg + 7372800;                   // end: 22.9M f = 91.7 MB

    hipLaunchKernelGGL(kprep_ab, dim3(352),  dim3(256), 0, stream, a1, a2, b1, b2, AB);
    hipLaunchKernelGGL(kprep_W,  dim3(4800), dim3(256), 0, stream, w1, w2, Wt);
    hipLaunchKernelGGL(ktr_x,    dim3(608),  dim3(256), 0, stream, X, Xp);
    // hop 1
    hipLaunchKernelGGL(kfuse, dim3(768), dim3(256), 0, stream, te, adjW, adjB, AB, Xp, Hagg);
    hipLaunchKernelGGL(kmm,   dim3(600), dim3(256), 0, stream, Hagg, Xp, Wt, H1);
    // hop 2
    hipLaunchKernelGGL(kfuse, dim3(768), dim3(256), 0, stream, te, adjW, adjB, AB, H1, Hagg);
    hipLaunchKernelGGL(kmm,   dim3(600), dim3(256), 0, stream, Hagg, Xp, Wt, Hagg); // in-place
    // gcn epilogue
    hipLaunchKernelGGL(kgcn,  dim3(608), dim3(256), 0, stream, Xp, H1, Hagg, gW, gB, out);
}

// Round 4
// 420.046 us; speedup vs baseline: 2.4077x; 1.5507x over previous
//
#include <hip/hip_runtime.h>

#define Nq 300
#define Tq 12
#define Dq 64
#define Mq 16
#define BTq 384
#define DDq (Dq*Dq)      // 4096
#define Fq (Dq*3)        // 192
#define NP 320           // padded k-extent of transposed bf16 buffers

typedef short bf8_t __attribute__((ext_vector_type(8)));
typedef float f4_t  __attribute__((ext_vector_type(4)));

__device__ __forceinline__ unsigned short f2bf(float f) {
    unsigned u = __float_as_uint(f);
    u = (u + 0x7FFFu + ((u >> 16) & 1u)) >> 16;
    return (unsigned short)u;
}
__device__ __forceinline__ float bf2f(unsigned short u) {
    return __uint_as_float((unsigned)u << 16);
}
__device__ __forceinline__ float4 ld4(const float* p) { return *(const float4*)p; }

__device__ __forceinline__ bf8_t pack8(float4 a, float4 b) {
    bf8_t r;
    r[0] = (short)f2bf(a.x); r[1] = (short)f2bf(a.y);
    r[2] = (short)f2bf(a.z); r[3] = (short)f2bf(a.w);
    r[4] = (short)f2bf(b.x); r[5] = (short)f2bf(b.y);
    r[6] = (short)f2bf(b.z); r[7] = (short)f2bf(b.w);
    return r;
}

__device__ __forceinline__ float gatef(float p) {
    float pc = fminf(fmaxf(p, -30.f), 30.f);
    float sig = 1.f / (1.f + __expf(-pc));
    float e2  = __expf(2.f * pc);
    float th  = (e2 - 1.f) / (e2 + 1.f);
    return sig * th;
}

// ABp[n*300+k] = bf16(beta1@beta2)[n,k] <<16 | bf16(alpha1@alpha2)[n,k]
__global__ void kprep_ab(const float* __restrict__ a1, const float* __restrict__ a2,
                         const float* __restrict__ b1, const float* __restrict__ b2,
                         unsigned* __restrict__ ABp) {
    int e = blockIdx.x * 256 + threadIdx.x;
    if (e >= Nq * Nq) return;
    int n = e / Nq, k = e - n * Nq;
    float sa = 0.f, sb = 0.f;
    #pragma unroll
    for (int m = 0; m < Mq; ++m) {
        sa = fmaf(a1[n*Mq+m], a2[m*Nq+k], sa);
        sb = fmaf(b1[n*Mq+m], b2[m*Nq+k], sb);
    }
    ABp[e] = ((unsigned)f2bf(sb) << 16) | (unsigned)f2bf(sa);
}

// Wt bf16 [n][d][k] = (trainW1@trainW2)[n, k*64+d]
__global__ void kprep_W(const float* __restrict__ w1, const float* __restrict__ w2,
                        unsigned short* __restrict__ Wt) {
    int e = blockIdx.x * 256 + threadIdx.x;
    if (e >= Nq * DDq) return;
    int n = e >> 12, i = e & (DDq - 1);
    int d = i >> 6, k = i & 63;
    float s = 0.f;
    #pragma unroll
    for (int m = 0; m < Mq; ++m) s = fmaf(w1[n*Mq+m], w2[m*DDq + k*Dq + d], s);
    Wt[e] = f2bf(s);
}

// adjWb bf16 [304][64], rows >=300 zero
__global__ void kprep_adjW(const float* __restrict__ adjW, unsigned short* __restrict__ adjWb) {
    int e = blockIdx.x * 256 + threadIdx.x;
    if (e >= 304 * 64) return;
    int k = e >> 6, d = e & 63;
    adjWb[e] = (k < Nq) ? f2bf(adjW[k*Dq + d]) : (unsigned short)0;
}

// te_b bf16 [bt][n][64] = timeEmbedding[b][n][t][d]
__global__ void __launch_bounds__(256) ktr_te(const float* __restrict__ te,
                                              unsigned short* __restrict__ te_b) {
    int i = blockIdx.x * 256 + threadIdx.x;   // 1,843,200 units of 4 elements
    int q = i & 15;
    int rem = i >> 4;
    int t = rem % Tq;
    int rem2 = rem / Tq;
    int n = rem2 % Nq;
    int b = rem2 / Nq;
    float4 v = ld4(&te[(((size_t)b*Nq + n)*Tq + t)*Dq + q*4]);
    ushort4 o;
    o.x = f2bf(v.x); o.y = f2bf(v.y); o.z = f2bf(v.z); o.w = f2bf(v.w);
    *(ushort4*)&te_b[(((size_t)(b*Tq + t))*Nq + n)*Dq + q*4] = o;
}

// X [b][d][n][t] -> Xp_t bf16 [bt][64][320] and Xp_nb bf16 [n][384][64]
__global__ void __launch_bounds__(256) ktr_x(const float* __restrict__ X,
                                             unsigned short* __restrict__ Xp_t,
                                             unsigned short* __restrict__ Xp_nb) {
    __shared__ unsigned short sT[64 * 308];   // [d][nl*12+t], stride 308
    const int b = blockIdx.x / 12, tile = blockIdx.x % 12;
    const int n0 = tile * 25;
    const int tid = threadIdx.x;
    for (int i = tid; i < 64 * 300; i += 256) {
        int d = i / 300, j = i - d * 300;     // j = nl*12 + t
        sT[d*308 + j] = f2bf(X[(size_t)(b*64 + d)*3600 + n0*12 + j]);
    }
    __syncthreads();
    // Xp_t[bt][d][n0+nl]
    for (int wi = tid; wi < 12 * 64 * 25; wi += 256) {
        int nl = wi % 25, rem = wi / 25;
        int d = rem % 64, t = rem / 64;
        Xp_t[((size_t)(b*Tq + t)*64 + d)*NP + n0 + nl] = sT[d*308 + nl*12 + t];
    }
    if (tile == 11) {   // zero pad cols 300..319
        for (int wi = tid; wi < 12 * 64 * 20; wi += 256) {
            int e = wi % 20, rem = wi / 20;
            int d = rem % 64, t = rem / 64;
            Xp_t[((size_t)(b*Tq + t)*64 + d)*NP + 300 + e] = 0;
        }
    }
    // Xp_nb[n][bt][d]
    for (int wi = tid; wi < 25 * 12 * 64; wi += 256) {
        int d = wi & 63, rem = wi >> 6;
        int t = rem % 12, nl = rem / 12;
        Xp_nb[((size_t)(n0 + nl)*BTq + b*Tq + t)*64 + d] = sT[d*308 + nl*12 + t];
    }
}

// bf16 transpose: H_nb [n][384][64] -> H_t [bt][64][320] (cols>=300 zero)
__global__ void __launch_bounds__(256) ktr2(const unsigned short* __restrict__ Hnb,
                                            unsigned short* __restrict__ Ht) {
    __shared__ unsigned short sT[64 * 308];
    const int bt = blockIdx.x;
    const int tid = threadIdx.x;
    for (int i = tid; i < 300 * 64; i += 256) {
        int n = i >> 6, d = i & 63;
        sT[d*308 + n] = Hnb[((size_t)n*BTq + bt)*64 + d];
    }
    __syncthreads();
    for (int wi = tid; wi < 64 * 80; wi += 256) {      // ushort4 over 320 cols
        int kq = wi % 80, d = wi / 80;
        ushort4 o;
        int k = kq * 4;
        o.x = (k+0 < Nq) ? sT[d*308 + k+0] : (unsigned short)0;
        o.y = (k+1 < Nq) ? sT[d*308 + k+1] : (unsigned short)0;
        o.z = (k+2 < Nq) ? sT[d*308 + k+2] : (unsigned short)0;
        o.w = (k+3 < Nq) ? sT[d*308 + k+3] : (unsigned short)0;
        *(ushort4*)&Ht[((size_t)bt*64 + d)*NP + k] = o;
    }
}

// Fused A-recompute + aggregation. grid 1536 = (bt, n-quarter of 80).
// Hout_nb[n][bt][d] = relu(AA.*sin(te@adjW^T+adjB)+BB) @ Hb  (bf16 MFMA)
__global__ void __launch_bounds__(256, 3) kfuse(
    const unsigned short* __restrict__ te_b,   // [bt][300][64]
    const unsigned short* __restrict__ adjWb,  // [304][64]
    const float* __restrict__ adjB,            // [300]
    const unsigned* __restrict__ ABp,          // [300][300]
    const unsigned short* __restrict__ Hb_t,   // [bt][64][320]
    unsigned short* __restrict__ Hout_nb)      // [300][384][64]
{
    __shared__ unsigned short sPl[80 * 72];
    const int bt = blockIdx.x >> 2, qi = blockIdx.x & 3;
    const int nbase = qi * 80;
    const int tid = threadIdx.x;
    const int w = tid >> 6, lane = tid & 63, quad = lane >> 4, l16 = lane & 15;
    const int dcol = w*16 + l16;

    bf8_t ta0[5], ta1[5];                       // hoisted te A-frags
    #pragma unroll
    for (int rt = 0; rt < 5; ++rt) {
        int nr = nbase + rt*16 + l16; if (nr > Nq-1) nr = Nq-1;
        const unsigned short* r = te_b + ((size_t)bt*Nq + nr)*64;
        ta0[rt] = *(const bf8_t*)(r + quad*8);
        ta1[rt] = *(const bf8_t*)(r + 32 + quad*8);
    }
    f4_t accO[5];
    #pragma unroll
    for (int rt = 0; rt < 5; ++rt) accO[rt] = (f4_t){0.f, 0.f, 0.f, 0.f};

    for (int c = 0; c < 5; ++c) {
        const int cbase = c * 64;
        const int kglob = cbase + w*16 + l16;
        const int kc = (kglob > Nq-1) ? Nq-1 : kglob;
        const float bias = adjB[kc];
        const unsigned short* ar = adjWb + kc*64;
        bf8_t kb0 = *(const bf8_t*)(ar + quad*8);
        bf8_t kb1 = *(const bf8_t*)(ar + 32 + quad*8);
        #pragma unroll
        for (int rt = 0; rt < 5; ++rt) {
            f4_t p = {0.f, 0.f, 0.f, 0.f};
            p = __builtin_amdgcn_mfma_f32_16x16x32_bf16(ta0[rt], kb0, p, 0, 0, 0);
            p = __builtin_amdgcn_mfma_f32_16x16x32_bf16(ta1[rt], kb1, p, 0, 0, 0);
            #pragma unroll
            for (int reg = 0; reg < 4; ++reg) {
                int nl = rt*16 + quad*4 + reg;
                int ncp = nbase + nl; if (ncp > Nq-1) ncp = Nq-1;
                unsigned ab = ABp[ncp*Nq + kc];
                float alo = __uint_as_float(ab << 16);
                float ahi = __uint_as_float(ab & 0xFFFF0000u);
                float sv = __sinf(p[reg] + bias);
                float a = fmaf(alo, sv, ahi);
                a = fmaxf(a, 0.f);
                if (kglob > Nq-1) a = 0.f;
                sPl[nl*72 + w*16 + l16] = f2bf(a);
            }
        }
        __syncthreads();
        const unsigned short* hr = Hb_t + ((size_t)bt*64 + dcol)*NP + cbase;
        bf8_t v0 = *(const bf8_t*)(hr + quad*8);
        bf8_t v1 = *(const bf8_t*)(hr + 32 + quad*8);
        #pragma unroll
        for (int rt = 0; rt < 5; ++rt) {
            bf8_t p0 = *(const bf8_t*)&sPl[(rt*16 + l16)*72 + quad*8];
            bf8_t p1 = *(const bf8_t*)&sPl[(rt*16 + l16)*72 + 32 + quad*8];
            accO[rt] = __builtin_amdgcn_mfma_f32_16x16x32_bf16(p0, v0, accO[rt], 0, 0, 0);
            accO[rt] = __builtin_amdgcn_mfma_f32_16x16x32_bf16(p1, v1, accO[rt], 0, 0, 0);
        }
        __syncthreads();
    }
    #pragma unroll
    for (int rt = 0; rt < 5; ++rt) {
        #pragma unroll
        for (int reg = 0; reg < 4; ++reg) {
            int ng = nbase + rt*16 + quad*4 + reg;
            if (ng < Nq)
                Hout_nb[((size_t)ng*BTq + bt)*64 + dcol] = f2bf(accO[rt][reg]);
        }
    }
}

// Per-node matmul + gate. grid 1200 = (n, bt-quarter of 96). In-place safe per block.
__global__ void __launch_bounds__(256) kmm(
    const unsigned short* __restrict__ Hagg_nb,  // [n][384][64]
    const unsigned short* __restrict__ Xp_nb,    // [n][384][64]
    const unsigned short* __restrict__ Wt,       // [n][64][64]
    unsigned short* __restrict__ Hout_nb)        // [n][384][64]
{
    const int n = blockIdx.x >> 2, qi = blockIdx.x & 3;
    const int bt0 = qi * 96;
    const int tid = threadIdx.x;
    const int w = tid >> 6, lane = tid & 63, quad = lane >> 4, l16 = lane & 15;
    const int dcol = w*16 + l16;
    const unsigned short* wn = Wt + (size_t)n * DDq + dcol*64;
    bf8_t v0 = *(const bf8_t*)(wn + quad*8);
    bf8_t v1 = *(const bf8_t*)(wn + 32 + quad*8);
    f4_t acc[6];
    #pragma unroll
    for (int rt = 0; rt < 6; ++rt) acc[rt] = (f4_t){0.f, 0.f, 0.f, 0.f};
    #pragma unroll
    for (int rt = 0; rt < 6; ++rt) {
        int r = bt0 + rt*16 + l16;
        const unsigned short* row = Hagg_nb + ((size_t)n*BTq + r)*64;
        bf8_t a0 = *(const bf8_t*)(row + quad*8);
        bf8_t a1 = *(const bf8_t*)(row + 32 + quad*8);
        acc[rt] = __builtin_amdgcn_mfma_f32_16x16x32_bf16(a0, v0, acc[rt], 0, 0, 0);
        acc[rt] = __builtin_amdgcn_mfma_f32_16x16x32_bf16(a1, v1, acc[rt], 0, 0, 0);
    }
    __syncthreads();
    #pragma unroll
    for (int rt = 0; rt < 6; ++rt) {
        #pragma unroll
        for (int reg = 0; reg < 4; ++reg) {
            int r = bt0 + rt*16 + quad*4 + reg;
            size_t idx = ((size_t)n*BTq + r)*64 + dcol;
            float xp = bf2f(Xp_nb[idx]);
            Hout_nb[idx] = f2bf(gatef(xp + acc[rt][reg]));
        }
    }
}

// GCN epilogue: out[b,d,n,t] = gcnB[d] + [Xp|H1|H2]@gcnW[d,:]. grid 608 = (b, n-tile 16).
__global__ void __launch_bounds__(256) kgcn(
    const unsigned short* __restrict__ Xp_nb, const unsigned short* __restrict__ H1_nb,
    const unsigned short* __restrict__ H2_nb, const float* __restrict__ gcnW,
    const float* __restrict__ gcnB, float* __restrict__ out)
{
    const int b = blockIdx.x / 19, tile = blockIdx.x % 19;
    const int n0 = tile * 16;
    const int rows = (tile == 18) ? 144 : 192;
    const int tid = threadIdx.x;
    const int w = tid >> 6, lane = tid & 63, quad = lane >> 4, l16 = lane & 15;
    const int dcol = w*16 + l16;
    const float bias = gcnB[dcol];
    f4_t acc[12];
    #pragma unroll
    for (int rt = 0; rt < 12; ++rt) acc[rt] = (f4_t){0.f, 0.f, 0.f, 0.f};
    const unsigned short* bufs[3] = {Xp_nb, H1_nb, H2_nb};
    #pragma unroll
    for (int c = 0; c < 3; ++c) {
        const unsigned short* buf = bufs[c];
        const float* gwr = gcnW + (size_t)dcol*Fq + c*Dq;
        bf8_t v0 = pack8(ld4(gwr + quad*8),      ld4(gwr + quad*8 + 4));
        bf8_t v1 = pack8(ld4(gwr + 32 + quad*8), ld4(gwr + 36 + quad*8));
        #pragma unroll 3
        for (int rt = 0; rt < 12; ++rt) {
            int r = rt*16 + l16;
            int nl = r / 12, t = r - nl*12;
            int n = n0 + nl; if (n > Nq-1) n = Nq-1;
            const unsigned short* row = buf + ((size_t)n*BTq + b*Tq + t)*64;
            bf8_t a0 = *(const bf8_t*)(row + quad*8);
            bf8_t a1 = *(const bf8_t*)(row + 32 + quad*8);
            acc[rt] = __builtin_amdgcn_mfma_f32_16x16x32_bf16(a0, v0, acc[rt], 0, 0, 0);
            acc[rt] = __builtin_amdgcn_mfma_f32_16x16x32_bf16(a1, v1, acc[rt], 0, 0, 0);
        }
    }
    float* outd = out + (size_t)(b*Dq + dcol)*3600 + n0*12;
    #pragma unroll
    for (int rt = 0; rt < 12; ++rt) {
        if (rt*16 >= rows) break;
        int r0 = rt*16 + quad*4;
        float4 o = make_float4(acc[rt][0] + bias, acc[rt][1] + bias,
                               acc[rt][2] + bias, acc[rt][3] + bias);
        *(float4*)&outd[r0] = o;
    }
}

extern "C" void kernel_launch(void* const* d_in, const int* in_sizes, int n_in,
                              void* d_out, int out_size, void* d_ws, size_t ws_size,
                              hipStream_t stream) {
    (void)in_sizes; (void)n_in; (void)out_size; (void)ws_size;
    const float* X    = (const float*)d_in[0];
    const float* te   = (const float*)d_in[1];
    const float* adjW = (const float*)d_in[2];
    const float* adjB = (const float*)d_in[3];
    const float* w1   = (const float*)d_in[4];
    const float* w2   = (const float*)d_in[5];
    const float* a1   = (const float*)d_in[6];
    const float* a2   = (const float*)d_in[7];
    const float* b1   = (const float*)d_in[8];
    const float* b2   = (const float*)d_in[9];
    const float* gW   = (const float*)d_in[10];
    const float* gB   = (const float*)d_in[11];
    float* out = (float*)d_out;

    char* ws = (char*)d_ws;
    unsigned*       ABp    = (unsigned*)      (ws);               //    360,064
    unsigned short* adjWb  = (unsigned short*)(ws + 360064);      //  +  38,912 = 398,976
    unsigned short* Wt     = (unsigned short*)(ws + 398976);      //  +2,457,600 = 2,856,576
    unsigned short* te_b   = (unsigned short*)(ws + 2856576);     // +14,745,600 = 17,602,176
    unsigned short* Xp_t   = (unsigned short*)(ws + 17602176);    // +15,728,640 = 33,330,816
    unsigned short* Xp_nb  = (unsigned short*)(ws + 33330816);    // +14,745,600 = 48,076,416
    unsigned short* Hagg   = (unsigned short*)(ws + 48076416);    // +14,745,600 = 62,822,016
    unsigned short* H1_nb  = (unsigned short*)(ws + 62822016);    // +14,745,600 = 77,567,616
    unsigned short* H1_t   = (unsigned short*)(ws + 77567616);    // +15,728,640 = 93,296,256 B

    hipLaunchKernelGGL(kprep_ab,   dim3(352),  dim3(256), 0, stream, a1, a2, b1, b2, ABp);
    hipLaunchKernelGGL(kprep_W,    dim3(4800), dim3(256), 0, stream, w1, w2, Wt);
    hipLaunchKernelGGL(kprep_adjW, dim3(76),   dim3(256), 0, stream, adjW, adjWb);
    hipLaunchKernelGGL(ktr_te,     dim3(7200), dim3(256), 0, stream, te, te_b);
    hipLaunchKernelGGL(ktr_x,      dim3(384),  dim3(256), 0, stream, X, Xp_t, Xp_nb);
    // hop 1
    hipLaunchKernelGGL(kfuse, dim3(1536), dim3(256), 0, stream, te_b, adjWb, adjB, ABp, Xp_t, Hagg);
    hipLaunchKernelGGL(kmm,   dim3(1200), dim3(256), 0, stream, Hagg, Xp_nb, Wt, H1_nb);
    hipLaunchKernelGGL(ktr2,  dim3(384),  dim3(256), 0, stream, H1_nb, H1_t);
    // hop 2
    hipLaunchKernelGGL(kfuse, dim3(1536), dim3(256), 0, stream, te_b, adjWb, adjB, ABp, H1_t, Hagg);
    hipLaunchKernelGGL(kmm,   dim3(1200), dim3(256), 0, stream, Hagg, Xp_nb, Wt, Hagg); // in-place -> H2
    // gcn epilogue
    hipLaunchKernelGGL(kgcn,  dim3(608), dim3(256), 0, stream, Xp_nb, H1_nb, Hagg, gW, gB, out);
}

// Round 5
// 330.314 us; speedup vs baseline: 3.0617x; 1.2717x over previous
//
#include <hip/hip_runtime.h>

#define Nq 300
#define Tq 12
#define Dq 64
#define Mq 16
#define BTq 384
#define DDq (Dq*Dq)      // 4096
#define Fq (Dq*3)        // 192
#define NP 320           // padded k-extent of transposed bf16 buffers

typedef short bf8_t __attribute__((ext_vector_type(8)));
typedef float f4_t  __attribute__((ext_vector_type(4)));

__device__ __forceinline__ unsigned short f2bf(float f) {
    unsigned u = __float_as_uint(f);
    u = (u + 0x7FFFu + ((u >> 16) & 1u)) >> 16;
    return (unsigned short)u;
}
__device__ __forceinline__ float bf2f(unsigned short u) {
    return __uint_as_float((unsigned)u << 16);
}
__device__ __forceinline__ float4 ld4(const float* p) { return *(const float4*)p; }

__device__ __forceinline__ bf8_t pack8(float4 a, float4 b) {
    bf8_t r;
    r[0] = (short)f2bf(a.x); r[1] = (short)f2bf(a.y);
    r[2] = (short)f2bf(a.z); r[3] = (short)f2bf(a.w);
    r[4] = (short)f2bf(b.x); r[5] = (short)f2bf(b.y);
    r[6] = (short)f2bf(b.z); r[7] = (short)f2bf(b.w);
    return r;
}

__device__ __forceinline__ float gatef(float p) {
    float pc = fminf(fmaxf(p, -30.f), 30.f);
    float sig = 1.f / (1.f + __expf(-pc));
    float e2  = __expf(2.f * pc);
    float th  = (e2 - 1.f) / (e2 + 1.f);
    return sig * th;
}

// ABp[n*300+k] = bf16(beta1@beta2)[n,k] <<16 | bf16(alpha1@alpha2)[n,k]
__global__ void kprep_ab(const float* __restrict__ a1, const float* __restrict__ a2,
                         const float* __restrict__ b1, const float* __restrict__ b2,
                         unsigned* __restrict__ ABp) {
    int e = blockIdx.x * 256 + threadIdx.x;
    if (e >= Nq * Nq) return;
    int n = e / Nq, k = e - n * Nq;
    float sa = 0.f, sb = 0.f;
    #pragma unroll
    for (int m = 0; m < Mq; ++m) {
        sa = fmaf(a1[n*Mq+m], a2[m*Nq+k], sa);
        sb = fmaf(b1[n*Mq+m], b2[m*Nq+k], sb);
    }
    ABp[e] = ((unsigned)f2bf(sb) << 16) | (unsigned)f2bf(sa);
}

// Wt bf16 [n][d][k] = (trainW1@trainW2)[n, k*64+d]
// One block per n; coalesced w2 reads; LDS transpose; coalesced stores.
__global__ void __launch_bounds__(256) kprep_W(const float* __restrict__ w1,
                                               const float* __restrict__ w2,
                                               unsigned short* __restrict__ Wt) {
    __shared__ float sT[64 * 65];     // [d][k], stride 65 (conflict-free)
    __shared__ float sw1[Mq];
    const int n = blockIdx.x;
    const int tid = threadIdx.x;
    if (tid < Mq) sw1[tid] = w1[n*Mq + tid];
    __syncthreads();
    for (int i = tid; i < DDq; i += 256) {     // i = k*64 + d (d minor -> coalesced)
        int k = i >> 6, d = i & 63;
        float s = 0.f;
        #pragma unroll
        for (int m = 0; m < Mq; ++m) s = fmaf(sw1[m], w2[m*DDq + i], s);
        sT[d*65 + k] = s;
    }
    __syncthreads();
    for (int i = tid; i < DDq; i += 256) {     // i = d*64 + k (k minor -> coalesced)
        int d = i >> 6, k = i & 63;
        Wt[(size_t)n*DDq + i] = f2bf(sT[d*65 + k]);
    }
}

// adjWb bf16 [304][64], rows >=300 zero
__global__ void kprep_adjW(const float* __restrict__ adjW, unsigned short* __restrict__ adjWb) {
    int e = blockIdx.x * 256 + threadIdx.x;
    if (e >= 304 * 64) return;
    int k = e >> 6, d = e & 63;
    adjWb[e] = (k < Nq) ? f2bf(adjW[k*Dq + d]) : (unsigned short)0;
}

// te_b bf16 [bt][n][64] = timeEmbedding[b][n][t][d]
__global__ void __launch_bounds__(256) ktr_te(const float* __restrict__ te,
                                              unsigned short* __restrict__ te_b) {
    int i = blockIdx.x * 256 + threadIdx.x;   // 1,843,200 units of 4 elements
    int q = i & 15;
    int rem = i >> 4;
    int t = rem % Tq;
    int rem2 = rem / Tq;
    int n = rem2 % Nq;
    int b = rem2 / Nq;
    float4 v = ld4(&te[(((size_t)b*Nq + n)*Tq + t)*Dq + q*4]);
    ushort4 o;
    o.x = f2bf(v.x); o.y = f2bf(v.y); o.z = f2bf(v.z); o.w = f2bf(v.w);
    *(ushort4*)&te_b[(((size_t)(b*Tq + t))*Nq + n)*Dq + q*4] = o;
}

// X [b][d][n][t] -> Xp_t bf16 [bt][64][320] and Xp_nb bf16 [n][384][64]
__global__ void __launch_bounds__(256) ktr_x(const float* __restrict__ X,
                                             unsigned short* __restrict__ Xp_t,
                                             unsigned short* __restrict__ Xp_nb) {
    __shared__ unsigned short sT[64 * 308];   // [d][nl*12+t], stride 308
    const int b = blockIdx.x / 12, tile = blockIdx.x % 12;
    const int n0 = tile * 25;
    const int tid = threadIdx.x;
    for (int i = tid; i < 64 * 300; i += 256) {
        int d = i / 300, j = i - d * 300;     // j = nl*12 + t
        sT[d*308 + j] = f2bf(X[(size_t)(b*64 + d)*3600 + n0*12 + j]);
    }
    __syncthreads();
    // Xp_t[bt][d][n0+nl]
    for (int wi = tid; wi < 12 * 64 * 25; wi += 256) {
        int nl = wi % 25, rem = wi / 25;
        int d = rem % 64, t = rem / 64;
        Xp_t[((size_t)(b*Tq + t)*64 + d)*NP + n0 + nl] = sT[d*308 + nl*12 + t];
    }
    if (tile == 11) {   // zero pad cols 300..319
        for (int wi = tid; wi < 12 * 64 * 20; wi += 256) {
            int e = wi % 20, rem = wi / 20;
            int d = rem % 64, t = rem / 64;
            Xp_t[((size_t)(b*Tq + t)*64 + d)*NP + 300 + e] = 0;
        }
    }
    // Xp_nb[n][bt][d]
    for (int wi = tid; wi < 25 * 12 * 64; wi += 256) {
        int d = wi & 63, rem = wi >> 6;
        int t = rem % 12, nl = rem / 12;
        Xp_nb[((size_t)(n0 + nl)*BTq + b*Tq + t)*64 + d] = sT[d*308 + nl*12 + t];
    }
}

// bf16 transpose: H_nb [n][384][64] -> H_t [bt][64][320] (cols>=300 zero)
__global__ void __launch_bounds__(256) ktr2(const unsigned short* __restrict__ Hnb,
                                            unsigned short* __restrict__ Ht) {
    __shared__ unsigned short sT[64 * 308];
    const int bt = blockIdx.x;
    const int tid = threadIdx.x;
    for (int i = tid; i < 300 * 64; i += 256) {
        int n = i >> 6, d = i & 63;
        sT[d*308 + n] = Hnb[((size_t)n*BTq + bt)*64 + d];
    }
    __syncthreads();
    for (int wi = tid; wi < 64 * 80; wi += 256) {      // ushort4 over 320 cols
        int kq = wi % 80, d = wi / 80;
        ushort4 o;
        int k = kq * 4;
        o.x = (k+0 < Nq) ? sT[d*308 + k+0] : (unsigned short)0;
        o.y = (k+1 < Nq) ? sT[d*308 + k+1] : (unsigned short)0;
        o.z = (k+2 < Nq) ? sT[d*308 + k+2] : (unsigned short)0;
        o.w = (k+3 < Nq) ? sT[d*308 + k+3] : (unsigned short)0;
        *(ushort4*)&Ht[((size_t)bt*64 + d)*NP + k] = o;
    }
}

// Fused A-recompute + aggregation. grid 1536 = (bt, n-quarter of 80).
// Hout_nb[n][bt][d] = relu(AA.*sin(te@adjW^T+adjB)+BB) @ Hb  (bf16 MFMA)
__global__ void __launch_bounds__(256, 3) kfuse(
    const unsigned short* __restrict__ te_b,   // [bt][300][64]
    const unsigned short* __restrict__ adjWb,  // [304][64]
    const float* __restrict__ adjB,            // [300]
    const unsigned* __restrict__ ABp,          // [300][300]
    const unsigned short* __restrict__ Hb_t,   // [bt][64][320]
    unsigned short* __restrict__ Hout_nb)      // [300][384][64]
{
    __shared__ unsigned short sPl[80 * 72];
    const int bt = blockIdx.x >> 2, qi = blockIdx.x & 3;
    const int nbase = qi * 80;
    const int tid = threadIdx.x;
    const int w = tid >> 6, lane = tid & 63, quad = lane >> 4, l16 = lane & 15;
    const int dcol = w*16 + l16;

    bf8_t ta0[5], ta1[5];                       // hoisted te A-frags
    #pragma unroll
    for (int rt = 0; rt < 5; ++rt) {
        int nr = nbase + rt*16 + l16; if (nr > Nq-1) nr = Nq-1;
        const unsigned short* r = te_b + ((size_t)bt*Nq + nr)*64;
        ta0[rt] = *(const bf8_t*)(r + quad*8);
        ta1[rt] = *(const bf8_t*)(r + 32 + quad*8);
    }
    f4_t accO[5];
    #pragma unroll
    for (int rt = 0; rt < 5; ++rt) accO[rt] = (f4_t){0.f, 0.f, 0.f, 0.f};

    for (int c = 0; c < 5; ++c) {
        const int cbase = c * 64;
        const int kglob = cbase + w*16 + l16;
        const int kc = (kglob > Nq-1) ? Nq-1 : kglob;
        const float bias = adjB[kc];
        const unsigned short* ar = adjWb + kc*64;
        bf8_t kb0 = *(const bf8_t*)(ar + quad*8);
        bf8_t kb1 = *(const bf8_t*)(ar + 32 + quad*8);
        #pragma unroll
        for (int rt = 0; rt < 5; ++rt) {
            f4_t p = {0.f, 0.f, 0.f, 0.f};
            p = __builtin_amdgcn_mfma_f32_16x16x32_bf16(ta0[rt], kb0, p, 0, 0, 0);
            p = __builtin_amdgcn_mfma_f32_16x16x32_bf16(ta1[rt], kb1, p, 0, 0, 0);
            #pragma unroll
            for (int reg = 0; reg < 4; ++reg) {
                int nl = rt*16 + quad*4 + reg;
                int ncp = nbase + nl; if (ncp > Nq-1) ncp = Nq-1;
                unsigned ab = ABp[ncp*Nq + kc];
                float alo = __uint_as_float(ab << 16);
                float ahi = __uint_as_float(ab & 0xFFFF0000u);
                float sv = __sinf(p[reg] + bias);
                float a = fmaf(alo, sv, ahi);
                a = fmaxf(a, 0.f);
                if (kglob > Nq-1) a = 0.f;
                sPl[nl*72 + w*16 + l16] = f2bf(a);
            }
        }
        __syncthreads();
        const unsigned short* hr = Hb_t + ((size_t)bt*64 + dcol)*NP + cbase;
        bf8_t v0 = *(const bf8_t*)(hr + quad*8);
        bf8_t v1 = *(const bf8_t*)(hr + 32 + quad*8);
        #pragma unroll
        for (int rt = 0; rt < 5; ++rt) {
            bf8_t p0 = *(const bf8_t*)&sPl[(rt*16 + l16)*72 + quad*8];
            bf8_t p1 = *(const bf8_t*)&sPl[(rt*16 + l16)*72 + 32 + quad*8];
            accO[rt] = __builtin_amdgcn_mfma_f32_16x16x32_bf16(p0, v0, accO[rt], 0, 0, 0);
            accO[rt] = __builtin_amdgcn_mfma_f32_16x16x32_bf16(p1, v1, accO[rt], 0, 0, 0);
        }
        __syncthreads();
    }
    #pragma unroll
    for (int rt = 0; rt < 5; ++rt) {
        #pragma unroll
        for (int reg = 0; reg < 4; ++reg) {
            int ng = nbase + rt*16 + quad*4 + reg;
            if (ng < Nq)
                Hout_nb[((size_t)ng*BTq + bt)*64 + dcol] = f2bf(accO[rt][reg]);
        }
    }
}

// Per-node matmul + gate. grid 1200 = (n, bt-quarter of 96). In-place safe per block.
__global__ void __launch_bounds__(256) kmm(
    const unsigned short* __restrict__ Hagg_nb,  // [n][384][64]
    const unsigned short* __restrict__ Xp_nb,    // [n][384][64]
    const unsigned short* __restrict__ Wt,       // [n][64][64]
    unsigned short* __restrict__ Hout_nb)        // [n][384][64]
{
    const int n = blockIdx.x >> 2, qi = blockIdx.x & 3;
    const int bt0 = qi * 96;
    const int tid = threadIdx.x;
    const int w = tid >> 6, lane = tid & 63, quad = lane >> 4, l16 = lane & 15;
    const int dcol = w*16 + l16;
    const unsigned short* wn = Wt + (size_t)n * DDq + dcol*64;
    bf8_t v0 = *(const bf8_t*)(wn + quad*8);
    bf8_t v1 = *(const bf8_t*)(wn + 32 + quad*8);
    f4_t acc[6];
    #pragma unroll
    for (int rt = 0; rt < 6; ++rt) acc[rt] = (f4_t){0.f, 0.f, 0.f, 0.f};
    #pragma unroll
    for (int rt = 0; rt < 6; ++rt) {
        int r = bt0 + rt*16 + l16;
        const unsigned short* row = Hagg_nb + ((size_t)n*BTq + r)*64;
        bf8_t a0 = *(const bf8_t*)(row + quad*8);
        bf8_t a1 = *(const bf8_t*)(row + 32 + quad*8);
        acc[rt] = __builtin_amdgcn_mfma_f32_16x16x32_bf16(a0, v0, acc[rt], 0, 0, 0);
        acc[rt] = __builtin_amdgcn_mfma_f32_16x16x32_bf16(a1, v1, acc[rt], 0, 0, 0);
    }
    __syncthreads();
    #pragma unroll
    for (int rt = 0; rt < 6; ++rt) {
        #pragma unroll
        for (int reg = 0; reg < 4; ++reg) {
            int r = bt0 + rt*16 + quad*4 + reg;
            size_t idx = ((size_t)n*BTq + r)*64 + dcol;
            float xp = bf2f(Xp_nb[idx]);
            Hout_nb[idx] = f2bf(gatef(xp + acc[rt][reg]));
        }
    }
}

// GCN epilogue: out[b,d,n,t] = gcnB[d] + [Xp|H1|H2]@gcnW[d,:]. grid 608 = (b, n-tile 16).
// NOTE: rt loops FULLY unrolled so acc[] stays in VGPRs (partial unroll spilled to scratch).
__global__ void __launch_bounds__(256) kgcn(
    const unsigned short* __restrict__ Xp_nb, const unsigned short* __restrict__ H1_nb,
    const unsigned short* __restrict__ H2_nb, const float* __restrict__ gcnW,
    const float* __restrict__ gcnB, float* __restrict__ out)
{
    const int b = blockIdx.x / 19, tile = blockIdx.x % 19;
    const int n0 = tile * 16;
    const int rows = (tile == 18) ? 144 : 192;
    const int tid = threadIdx.x;
    const int w = tid >> 6, lane = tid & 63, quad = lane >> 4, l16 = lane & 15;
    const int dcol = w*16 + l16;
    const float bias = gcnB[dcol];
    f4_t acc[12];
    #pragma unroll
    for (int rt = 0; rt < 12; ++rt) acc[rt] = (f4_t){0.f, 0.f, 0.f, 0.f};
    const unsigned short* bufs[3] = {Xp_nb, H1_nb, H2_nb};
    #pragma unroll
    for (int c = 0; c < 3; ++c) {
        const unsigned short* buf = bufs[c];
        const float* gwr = gcnW + (size_t)dcol*Fq + c*Dq;
        bf8_t v0 = pack8(ld4(gwr + quad*8),      ld4(gwr + quad*8 + 4));
        bf8_t v1 = pack8(ld4(gwr + 32 + quad*8), ld4(gwr + 36 + quad*8));
        #pragma unroll
        for (int rt = 0; rt < 12; ++rt) {
            int r = rt*16 + l16;
            int nl = r / 12, t = r - nl*12;
            int n = n0 + nl; if (n > Nq-1) n = Nq-1;
            const unsigned short* row = buf + ((size_t)n*BTq + b*Tq + t)*64;
            bf8_t a0 = *(const bf8_t*)(row + quad*8);
            bf8_t a1 = *(const bf8_t*)(row + 32 + quad*8);
            acc[rt] = __builtin_amdgcn_mfma_f32_16x16x32_bf16(a0, v0, acc[rt], 0, 0, 0);
            acc[rt] = __builtin_amdgcn_mfma_f32_16x16x32_bf16(a1, v1, acc[rt], 0, 0, 0);
        }
    }
    float* outd = out + (size_t)(b*Dq + dcol)*3600 + n0*12;
    #pragma unroll
    for (int rt = 0; rt < 12; ++rt) {
        if (rt*16 < rows) {
            int r0 = rt*16 + quad*4;
            float4 o = make_float4(acc[rt][0] + bias, acc[rt][1] + bias,
                                   acc[rt][2] + bias, acc[rt][3] + bias);
            *(float4*)&outd[r0] = o;
        }
    }
}

extern "C" void kernel_launch(void* const* d_in, const int* in_sizes, int n_in,
                              void* d_out, int out_size, void* d_ws, size_t ws_size,
                              hipStream_t stream) {
    (void)in_sizes; (void)n_in; (void)out_size; (void)ws_size;
    const float* X    = (const float*)d_in[0];
    const float* te   = (const float*)d_in[1];
    const float* adjW = (const float*)d_in[2];
    const float* adjB = (const float*)d_in[3];
    const float* w1   = (const float*)d_in[4];
    const float* w2   = (const float*)d_in[5];
    const float* a1   = (const float*)d_in[6];
    const float* a2   = (const float*)d_in[7];
    const float* b1   = (const float*)d_in[8];
    const float* b2   = (const float*)d_in[9];
    const float* gW   = (const float*)d_in[10];
    const float* gB   = (const float*)d_in[11];
    float* out = (float*)d_out;

    char* ws = (char*)d_ws;
    unsigned*       ABp    = (unsigned*)      (ws);               //    360,064
    unsigned short* adjWb  = (unsigned short*)(ws + 360064);      //  +  38,912 = 398,976
    unsigned short* Wt     = (unsigned short*)(ws + 398976);      //  +2,457,600 = 2,856,576
    unsigned short* te_b   = (unsigned short*)(ws + 2856576);     // +14,745,600 = 17,602,176
    unsigned short* Xp_t   = (unsigned short*)(ws + 17602176);    // +15,728,640 = 33,330,816
    unsigned short* Xp_nb  = (unsigned short*)(ws + 33330816);    // +14,745,600 = 48,076,416
    unsigned short* Hagg   = (unsigned short*)(ws + 48076416);    // +14,745,600 = 62,822,016
    unsigned short* H1_nb  = (unsigned short*)(ws + 62822016);    // +14,745,600 = 77,567,616
    unsigned short* H1_t   = (unsigned short*)(ws + 77567616);    // +15,728,640 = 93,296,256 B

    hipLaunchKernelGGL(kprep_ab,   dim3(352),  dim3(256), 0, stream, a1, a2, b1, b2, ABp);
    hipLaunchKernelGGL(kprep_W,    dim3(300),  dim3(256), 0, stream, w1, w2, Wt);
    hipLaunchKernelGGL(kprep_adjW, dim3(76),   dim3(256), 0, stream, adjW, adjWb);
    hipLaunchKernelGGL(ktr_te,     dim3(7200), dim3(256), 0, stream, te, te_b);
    hipLaunchKernelGGL(ktr_x,      dim3(384),  dim3(256), 0, stream, X, Xp_t, Xp_nb);
    // hop 1
    hipLaunchKernelGGL(kfuse, dim3(1536), dim3(256), 0, stream, te_b, adjWb, adjB, ABp, Xp_t, Hagg);
    hipLaunchKernelGGL(kmm,   dim3(1200), dim3(256), 0, stream, Hagg, Xp_nb, Wt, H1_nb);
    hipLaunchKernelGGL(ktr2,  dim3(384),  dim3(256), 0, stream, H1_nb, H1_t);
    // hop 2
    hipLaunchKernelGGL(kfuse, dim3(1536), dim3(256), 0, stream, te_b, adjWb, adjB, ABp, H1_t, Hagg);
    hipLaunchKernelGGL(kmm,   dim3(1200), dim3(256), 0, stream, Hagg, Xp_nb, Wt, Hagg); // in-place -> H2
    // gcn epilogue
    hipLaunchKernelGGL(kgcn,  dim3(608), dim3(256), 0, stream, Xp_nb, H1_nb, Hagg, gW, gB, out);
}

// Round 6
// 327.886 us; speedup vs baseline: 3.0844x; 1.0074x over previous
//
#include <hip/hip_runtime.h>

#define Nq 300
#define Tq 12
#define Dq 64
#define Mq 16
#define BTq 384
#define DDq (Dq*Dq)      // 4096
#define Fq (Dq*3)        // 192
#define NP 320           // padded k-extent of transposed bf16 buffers

typedef short bf8_t __attribute__((ext_vector_type(8)));
typedef float f4_t  __attribute__((ext_vector_type(4)));

__device__ __forceinline__ unsigned short f2bf(float f) {
    unsigned u = __float_as_uint(f);
    u = (u + 0x7FFFu + ((u >> 16) & 1u)) >> 16;
    return (unsigned short)u;
}
__device__ __forceinline__ float bf2f(unsigned short u) {
    return __uint_as_float((unsigned)u << 16);
}
__device__ __forceinline__ float4 ld4(const float* p) { return *(const float4*)p; }

__device__ __forceinline__ bf8_t pack8(float4 a, float4 b) {
    bf8_t r;
    r[0] = (short)f2bf(a.x); r[1] = (short)f2bf(a.y);
    r[2] = (short)f2bf(a.z); r[3] = (short)f2bf(a.w);
    r[4] = (short)f2bf(b.x); r[5] = (short)f2bf(b.y);
    r[6] = (short)f2bf(b.z); r[7] = (short)f2bf(b.w);
    return r;
}

__device__ __forceinline__ float gatef(float p) {
    float pc = fminf(fmaxf(p, -30.f), 30.f);
    float sig = 1.f / (1.f + __expf(-pc));
    float e2  = __expf(2.f * pc);
    float th  = (e2 - 1.f) / (e2 + 1.f);
    return sig * th;
}

// ABt: MFMA-C-tiled (alpha|beta) pairs. tile = ((qi*5+c)*4+w)*5+nt ; element lane*4+reg.
// n = qi*80+nt*16+(lane&15), k = c*64+w*16+(lane>>4)*4+reg. Zero outside 300x300.
__global__ void kprep_abt(const float* __restrict__ a1, const float* __restrict__ a2,
                          const float* __restrict__ b1, const float* __restrict__ b2,
                          unsigned* __restrict__ ABt) {
    const int tile = blockIdx.x;           // 0..399
    const int tid  = threadIdx.x;          // 0..255
    const int reg = tid & 3, lane = tid >> 2;
    const int nt = tile % 5;  int r1 = tile / 5;
    const int w  = r1 % 4;    int r2 = r1 / 4;
    const int c  = r2 % 5;    const int qi = r2 / 5;
    const int n = qi*80 + nt*16 + (lane & 15);
    const int k = c*64 + w*16 + (lane >> 4)*4 + reg;
    unsigned outv = 0u;
    if (n < Nq && k < Nq) {
        float sa = 0.f, sb = 0.f;
        #pragma unroll
        for (int m = 0; m < Mq; ++m) {
            sa = fmaf(a1[n*Mq+m], a2[m*Nq+k], sa);
            sb = fmaf(b1[n*Mq+m], b2[m*Nq+k], sb);
        }
        outv = ((unsigned)f2bf(sb) << 16) | (unsigned)f2bf(sa);
    }
    ABt[tile*256 + tid] = outv;
}

// Wt bf16 [n][d][k] = (trainW1@trainW2)[n, k*64+d]
__global__ void __launch_bounds__(256) kprep_W(const float* __restrict__ w1,
                                               const float* __restrict__ w2,
                                               unsigned short* __restrict__ Wt) {
    __shared__ float sT[64 * 65];
    __shared__ float sw1[Mq];
    const int n = blockIdx.x;
    const int tid = threadIdx.x;
    if (tid < Mq) sw1[tid] = w1[n*Mq + tid];
    __syncthreads();
    for (int i = tid; i < DDq; i += 256) {
        int k = i >> 6, d = i & 63;
        float s = 0.f;
        #pragma unroll
        for (int m = 0; m < Mq; ++m) s = fmaf(sw1[m], w2[m*DDq + i], s);
        sT[d*65 + k] = s;
    }
    __syncthreads();
    for (int i = tid; i < DDq; i += 256) {
        int d = i >> 6, k = i & 63;
        Wt[(size_t)n*DDq + i] = f2bf(sT[d*65 + k]);
    }
}

// adjWb bf16 [320][64] zero-padded; adjBp fp32 [320] zero-padded.
__global__ void kprep_adjW(const float* __restrict__ adjW, const float* __restrict__ adjB,
                           unsigned short* __restrict__ adjWb, float* __restrict__ adjBp) {
    int e = blockIdx.x * 256 + threadIdx.x;
    if (e < NP * 64) {
        int k = e >> 6, d = e & 63;
        adjWb[e] = (k < Nq) ? f2bf(adjW[k*Dq + d]) : (unsigned short)0;
    }
    if (e < NP) adjBp[e] = (e < Nq) ? adjB[e] : 0.f;
}

// X [b][d][n][t] -> Xp_t bf16 [bt][64][320] and Xp_nb bf16 [n][384][64]
__global__ void __launch_bounds__(256) ktr_x(const float* __restrict__ X,
                                             unsigned short* __restrict__ Xp_t,
                                             unsigned short* __restrict__ Xp_nb) {
    __shared__ unsigned short sT[64 * 308];
    const int b = blockIdx.x / 12, tile = blockIdx.x % 12;
    const int n0 = tile * 25;
    const int tid = threadIdx.x;
    for (int i = tid; i < 64 * 300; i += 256) {
        int d = i / 300, j = i - d * 300;
        sT[d*308 + j] = f2bf(X[(size_t)(b*64 + d)*3600 + n0*12 + j]);
    }
    __syncthreads();
    for (int wi = tid; wi < 12 * 64 * 25; wi += 256) {
        int nl = wi % 25, rem = wi / 25;
        int d = rem % 64, t = rem / 64;
        Xp_t[((size_t)(b*Tq + t)*64 + d)*NP + n0 + nl] = sT[d*308 + nl*12 + t];
    }
    if (tile == 11) {
        for (int wi = tid; wi < 12 * 64 * 20; wi += 256) {
            int e = wi % 20, rem = wi / 20;
            int d = rem % 64, t = rem / 64;
            Xp_t[((size_t)(b*Tq + t)*64 + d)*NP + 300 + e] = 0;
        }
    }
    for (int wi = tid; wi < 25 * 12 * 64; wi += 256) {
        int d = wi & 63, rem = wi >> 6;
        int t = rem % 12, nl = rem / 12;
        Xp_nb[((size_t)(n0 + nl)*BTq + b*Tq + t)*64 + d] = sT[d*308 + nl*12 + t];
    }
}

// bf16 transpose: H_nb [n][384][64] -> H_t [bt][64][320] (cols>=300 zero)
__global__ void __launch_bounds__(256) ktr2(const unsigned short* __restrict__ Hnb,
                                            unsigned short* __restrict__ Ht) {
    __shared__ unsigned short sT[64 * 308];
    const int bt = blockIdx.x;
    const int tid = threadIdx.x;
    for (int i = tid; i < 300 * 64; i += 256) {
        int n = i >> 6, d = i & 63;
        sT[d*308 + n] = Hnb[((size_t)n*BTq + bt)*64 + d];
    }
    __syncthreads();
    for (int wi = tid; wi < 64 * 80; wi += 256) {
        int kq = wi % 80, d = wi / 80;
        ushort4 o;
        int k = kq * 4;
        o.x = (k+0 < Nq) ? sT[d*308 + k+0] : (unsigned short)0;
        o.y = (k+1 < Nq) ? sT[d*308 + k+1] : (unsigned short)0;
        o.z = (k+2 < Nq) ? sT[d*308 + k+2] : (unsigned short)0;
        o.w = (k+3 < Nq) ? sT[d*308 + k+3] : (unsigned short)0;
        *(ushort4*)&Ht[((size_t)bt*64 + d)*NP + k] = o;
    }
}

// Fused A-recompute + aggregation, transposed GEMM1 (P^T), tiled AB, no clamps.
// grid 1536 = (bt, n-quarter of 80); LDS = double-buffered P^T tile 2x11520 B.
__global__ void __launch_bounds__(256) kfuse(
    const float* __restrict__ te,              // [B,N,T,D] fp32 (original input)
    const unsigned short* __restrict__ adjWb,  // [320][64]
    const float* __restrict__ adjBp,           // [320]
    const unsigned* __restrict__ ABt,          // tiled pairs
    const unsigned short* __restrict__ Hb_t,   // [bt][64][320]
    unsigned short* __restrict__ Hout_nb)      // [300][384][64]
{
    __shared__ unsigned short sPl[2][80 * 72];
    const int bt = blockIdx.x >> 2, qi = blockIdx.x & 3;
    const int b = bt / Tq, t = bt - b * Tq;
    const int nbase = qi * 80;
    const int tid = threadIdx.x;
    const int w = tid >> 6, lane = tid & 63, quad = lane >> 4, l16 = lane & 15;
    const int dcol = w*16 + l16;

    // hoisted te B-frags: col n = l16 (per ntile), contraction d — direct from fp32
    bf8_t tb0[5], tb1[5];
    #pragma unroll
    for (int nt = 0; nt < 5; ++nt) {
        int n = nbase + nt*16 + l16; if (n > Nq-1) n = Nq-1;   // addr safety; AB zeros kill value
        const float* ter = te + (((size_t)b*Nq + n)*Tq + t)*Dq;
        tb0[nt] = pack8(ld4(ter + quad*8),      ld4(ter + quad*8 + 4));
        tb1[nt] = pack8(ld4(ter + 32 + quad*8), ld4(ter + 36 + quad*8));
    }
    f4_t accO[5];
    #pragma unroll
    for (int rt = 0; rt < 5; ++rt) accO[rt] = (f4_t){0.f, 0.f, 0.f, 0.f};

    for (int c = 0; c < 5; ++c) {
        const int cbase = c * 64;
        // GEMM1': wave w owns k-tile; A = adjW rows k, B = te cols n  ->  C = P^T[k][n]
        const unsigned short* ar = adjWb + (cbase + w*16 + l16)*64;
        bf8_t ka0 = *(const bf8_t*)(ar + quad*8);
        bf8_t ka1 = *(const bf8_t*)(ar + 32 + quad*8);
        float4 bias4 = ld4(adjBp + cbase + w*16 + quad*4);
        const unsigned* abbase = ABt + ((((size_t)qi*5 + c)*4 + w)*5)*256 + lane*4;
        unsigned short* sp = sPl[c & 1];
        #pragma unroll
        for (int nt = 0; nt < 5; ++nt) {
            f4_t p = {0.f, 0.f, 0.f, 0.f};
            p = __builtin_amdgcn_mfma_f32_16x16x32_bf16(ka0, tb0[nt], p, 0, 0, 0);
            p = __builtin_amdgcn_mfma_f32_16x16x32_bf16(ka1, tb1[nt], p, 0, 0, 0);
            uint4 ab = *(const uint4*)(abbase + nt*256);
            ushort4 o4;
            {
                float sv = __sinf(p[0] + bias4.x);
                o4.x = f2bf(fmaxf(fmaf(__uint_as_float(ab.x << 16), sv,
                                       __uint_as_float(ab.x & 0xFFFF0000u)), 0.f));
            }
            {
                float sv = __sinf(p[1] + bias4.y);
                o4.y = f2bf(fmaxf(fmaf(__uint_as_float(ab.y << 16), sv,
                                       __uint_as_float(ab.y & 0xFFFF0000u)), 0.f));
            }
            {
                float sv = __sinf(p[2] + bias4.z);
                o4.z = f2bf(fmaxf(fmaf(__uint_as_float(ab.z << 16), sv,
                                       __uint_as_float(ab.z & 0xFFFF0000u)), 0.f));
            }
            {
                float sv = __sinf(p[3] + bias4.w);
                o4.w = f2bf(fmaxf(fmaf(__uint_as_float(ab.w << 16), sv,
                                       __uint_as_float(ab.w & 0xFFFF0000u)), 0.f));
            }
            // P^T[k][n] -> store at P[n=nt*16+l16][k-local = w*16+quad*4 .. +3]
            *(ushort4*)&sp[(nt*16 + l16)*72 + w*16 + quad*4] = o4;
        }
        __syncthreads();
        // GEMM2: wave w owns d-tile; A = P rows n (b128 from LDS), B = Hb cols d
        const unsigned short* hr = Hb_t + ((size_t)bt*64 + dcol)*NP + cbase;
        bf8_t v0 = *(const bf8_t*)(hr + quad*8);
        bf8_t v1 = *(const bf8_t*)(hr + 32 + quad*8);
        #pragma unroll
        for (int rt = 0; rt < 5; ++rt) {
            bf8_t p0 = *(const bf8_t*)&sp[(rt*16 + l16)*72 + quad*8];
            bf8_t p1 = *(const bf8_t*)&sp[(rt*16 + l16)*72 + 32 + quad*8];
            accO[rt] = __builtin_amdgcn_mfma_f32_16x16x32_bf16(p0, v0, accO[rt], 0, 0, 0);
            accO[rt] = __builtin_amdgcn_mfma_f32_16x16x32_bf16(p1, v1, accO[rt], 0, 0, 0);
        }
        // no 2nd barrier: next chunk writes the other sPl buffer; barrier ordering protects reuse
    }
    #pragma unroll
    for (int rt = 0; rt < 5; ++rt) {
        #pragma unroll
        for (int reg = 0; reg < 4; ++reg) {
            int ng = nbase + rt*16 + quad*4 + reg;
            if (ng < Nq)
                Hout_nb[((size_t)ng*BTq + bt)*64 + dcol] = f2bf(accO[rt][reg]);
        }
    }
}

// Per-node matmul + gate. grid 1200 = (n, bt-quarter of 96). In-place safe per block.
__global__ void __launch_bounds__(256) kmm(
    const unsigned short* __restrict__ Hagg_nb,  // [n][384][64]
    const unsigned short* __restrict__ Xp_nb,    // [n][384][64]
    const unsigned short* __restrict__ Wt,       // [n][64][64]
    unsigned short* __restrict__ Hout_nb)        // [n][384][64]
{
    const int n = blockIdx.x >> 2, qi = blockIdx.x & 3;
    const int bt0 = qi * 96;
    const int tid = threadIdx.x;
    const int w = tid >> 6, lane = tid & 63, quad = lane >> 4, l16 = lane & 15;
    const int dcol = w*16 + l16;
    const unsigned short* wn = Wt + (size_t)n * DDq + dcol*64;
    bf8_t v0 = *(const bf8_t*)(wn + quad*8);
    bf8_t v1 = *(const bf8_t*)(wn + 32 + quad*8);
    f4_t acc[6];
    #pragma unroll
    for (int rt = 0; rt < 6; ++rt) acc[rt] = (f4_t){0.f, 0.f, 0.f, 0.f};
    #pragma unroll
    for (int rt = 0; rt < 6; ++rt) {
        int r = bt0 + rt*16 + l16;
        const unsigned short* row = Hagg_nb + ((size_t)n*BTq + r)*64;
        bf8_t a0 = *(const bf8_t*)(row + quad*8);
        bf8_t a1 = *(const bf8_t*)(row + 32 + quad*8);
        acc[rt] = __builtin_amdgcn_mfma_f32_16x16x32_bf16(a0, v0, acc[rt], 0, 0, 0);
        acc[rt] = __builtin_amdgcn_mfma_f32_16x16x32_bf16(a1, v1, acc[rt], 0, 0, 0);
    }
    __syncthreads();
    #pragma unroll
    for (int rt = 0; rt < 6; ++rt) {
        #pragma unroll
        for (int reg = 0; reg < 4; ++reg) {
            int r = bt0 + rt*16 + quad*4 + reg;
            size_t idx = ((size_t)n*BTq + r)*64 + dcol;
            float xp = bf2f(Xp_nb[idx]);
            Hout_nb[idx] = f2bf(gatef(xp + acc[rt][reg]));
        }
    }
}

// GCN epilogue: out[b,d,n,t] = gcnB[d] + [Xp|H1|H2]@gcnW[d,:]. grid 608 = (b, n-tile 16).
__global__ void __launch_bounds__(256) kgcn(
    const unsigned short* __restrict__ Xp_nb, const unsigned short* __restrict__ H1_nb,
    const unsigned short* __restrict__ H2_nb, const float* __restrict__ gcnW,
    const float* __restrict__ gcnB, float* __restrict__ out)
{
    const int b = blockIdx.x / 19, tile = blockIdx.x % 19;
    const int n0 = tile * 16;
    const int rows = (tile == 18) ? 144 : 192;
    const int tid = threadIdx.x;
    const int w = tid >> 6, lane = tid & 63, quad = lane >> 4, l16 = lane & 15;
    const int dcol = w*16 + l16;
    const float bias = gcnB[dcol];
    f4_t acc[12];
    #pragma unroll
    for (int rt = 0; rt < 12; ++rt) acc[rt] = (f4_t){0.f, 0.f, 0.f, 0.f};
    const unsigned short* bufs[3] = {Xp_nb, H1_nb, H2_nb};
    #pragma unroll
    for (int c = 0; c < 3; ++c) {
        const unsigned short* buf = bufs[c];
        const float* gwr = gcnW + (size_t)dcol*Fq + c*Dq;
        bf8_t v0 = pack8(ld4(gwr + quad*8),      ld4(gwr + quad*8 + 4));
        bf8_t v1 = pack8(ld4(gwr + 32 + quad*8), ld4(gwr + 36 + quad*8));
        #pragma unroll
        for (int rt = 0; rt < 12; ++rt) {
            int r = rt*16 + l16;
            int nl = r / 12, t = r - nl*12;
            int n = n0 + nl; if (n > Nq-1) n = Nq-1;
            const unsigned short* row = buf + ((size_t)n*BTq + b*Tq + t)*64;
            bf8_t a0 = *(const bf8_t*)(row + quad*8);
            bf8_t a1 = *(const bf8_t*)(row + 32 + quad*8);
            acc[rt] = __builtin_amdgcn_mfma_f32_16x16x32_bf16(a0, v0, acc[rt], 0, 0, 0);
            acc[rt] = __builtin_amdgcn_mfma_f32_16x16x32_bf16(a1, v1, acc[rt], 0, 0, 0);
        }
    }
    float* outd = out + (size_t)(b*Dq + dcol)*3600 + n0*12;
    #pragma unroll
    for (int rt = 0; rt < 12; ++rt) {
        if (rt*16 < rows) {
            int r0 = rt*16 + quad*4;
            float4 o = make_float4(acc[rt][0] + bias, acc[rt][1] + bias,
                                   acc[rt][2] + bias, acc[rt][3] + bias);
            *(float4*)&outd[r0] = o;
        }
    }
}

extern "C" void kernel_launch(void* const* d_in, const int* in_sizes, int n_in,
                              void* d_out, int out_size, void* d_ws, size_t ws_size,
                              hipStream_t stream) {
    (void)in_sizes; (void)n_in; (void)out_size; (void)ws_size;
    const float* X    = (const float*)d_in[0];
    const float* te   = (const float*)d_in[1];
    const float* adjW = (const float*)d_in[2];
    const float* adjB = (const float*)d_in[3];
    const float* w1   = (const float*)d_in[4];
    const float* w2   = (const float*)d_in[5];
    const float* a1   = (const float*)d_in[6];
    const float* a2   = (const float*)d_in[7];
    const float* b1   = (const float*)d_in[8];
    const float* b2   = (const float*)d_in[9];
    const float* gW   = (const float*)d_in[10];
    const float* gB   = (const float*)d_in[11];
    float* out = (float*)d_out;

    char* ws = (char*)d_ws;
    unsigned*       ABt    = (unsigned*)      (ws);               //    409,600
    unsigned short* adjWb  = (unsigned short*)(ws + 409600);      //  +  40,960 =    450,560
    float*          adjBp  = (float*)         (ws + 450560);      //  +   1,280 =    451,840
    unsigned short* Wt     = (unsigned short*)(ws + 451840);      //  +2,457,600 =  2,909,440
    unsigned short* Xp_t   = (unsigned short*)(ws + 2909440);     // +15,728,640 = 18,638,080
    unsigned short* Xp_nb  = (unsigned short*)(ws + 18638080);    // +14,745,600 = 33,383,680
    unsigned short* Hagg   = (unsigned short*)(ws + 33383680);    // +14,745,600 = 48,129,280
    unsigned short* H1_nb  = (unsigned short*)(ws + 48129280);    // +14,745,600 = 62,874,880
    unsigned short* H1_t   = (unsigned short*)(ws + 62874880);    // +15,728,640 = 78,603,520 B

    hipLaunchKernelGGL(kprep_abt,  dim3(400), dim3(256), 0, stream, a1, a2, b1, b2, ABt);
    hipLaunchKernelGGL(kprep_W,    dim3(300), dim3(256), 0, stream, w1, w2, Wt);
    hipLaunchKernelGGL(kprep_adjW, dim3(80),  dim3(256), 0, stream, adjW, adjB, adjWb, adjBp);
    hipLaunchKernelGGL(ktr_x,      dim3(384), dim3(256), 0, stream, X, Xp_t, Xp_nb);
    // hop 1
    hipLaunchKernelGGL(kfuse, dim3(1536), dim3(256), 0, stream, te, adjWb, adjBp, ABt, Xp_t, Hagg);
    hipLaunchKernelGGL(kmm,   dim3(1200), dim3(256), 0, stream, Hagg, Xp_nb, Wt, H1_nb);
    hipLaunchKernelGGL(ktr2,  dim3(384),  dim3(256), 0, stream, H1_nb, H1_t);
    // hop 2
    hipLaunchKernelGGL(kfuse, dim3(1536), dim3(256), 0, stream, te, adjWb, adjBp, ABt, H1_t, Hagg);
    hipLaunchKernelGGL(kmm,   dim3(1200), dim3(256), 0, stream, Hagg, Xp_nb, Wt, Hagg); // in-place -> H2
    // gcn epilogue
    hipLaunchKernelGGL(kgcn,  dim3(608), dim3(256), 0, stream, Xp_nb, H1_nb, Hagg, gW, gB, out);
}

// Round 7
// 324.568 us; speedup vs baseline: 3.1159x; 1.0102x over previous
//
#include <hip/hip_runtime.h>

#define Nq 300
#define Tq 12
#define Dq 64
#define Mq 16
#define BTq 384
#define DDq (Dq*Dq)      // 4096
#define Fq (Dq*3)        // 192
#define NP 320           // padded k-extent of transposed bf16 buffers

typedef short bf8_t __attribute__((ext_vector_type(8)));
typedef float f4_t  __attribute__((ext_vector_type(4)));

__device__ __forceinline__ unsigned short f2bf(float f) {
    unsigned u = __float_as_uint(f);
    u = (u + 0x7FFFu + ((u >> 16) & 1u)) >> 16;
    return (unsigned short)u;
}
__device__ __forceinline__ float bf2f(unsigned short u) {
    return __uint_as_float((unsigned)u << 16);
}
__device__ __forceinline__ float4 ld4(const float* p) { return *(const float4*)p; }

__device__ __forceinline__ bf8_t pack8(float4 a, float4 b) {
    bf8_t r;
    r[0] = (short)f2bf(a.x); r[1] = (short)f2bf(a.y);
    r[2] = (short)f2bf(a.z); r[3] = (short)f2bf(a.w);
    r[4] = (short)f2bf(b.x); r[5] = (short)f2bf(b.y);
    r[6] = (short)f2bf(b.z); r[7] = (short)f2bf(b.w);
    return r;
}

__device__ __forceinline__ float gatef(float p) {
    float pc = fminf(fmaxf(p, -30.f), 30.f);
    float sig = 1.f / (1.f + __expf(-pc));
    float e2  = __expf(2.f * pc);
    float th  = (e2 - 1.f) / (e2 + 1.f);
    return sig * th;
}

// ---- Merged front-end: 1164 blocks.
//  [0,400)    ABt tiles (MFMA-C-tiled alpha/beta pairs)
//  [400,700)  Wt per-node weights (n = vb-400)
//  [700,780)  adjWb/adjBp padding
//  [780,1164) X transpose -> Xp_t, Xp_nb
__global__ void __launch_bounds__(256) kprep_all(
    const float* __restrict__ a1, const float* __restrict__ a2,
    const float* __restrict__ b1, const float* __restrict__ b2,
    const float* __restrict__ w1, const float* __restrict__ w2,
    const float* __restrict__ adjW, const float* __restrict__ adjB,
    const float* __restrict__ X,
    unsigned* __restrict__ ABt, unsigned short* __restrict__ Wt,
    unsigned short* __restrict__ adjWb, float* __restrict__ adjBp,
    unsigned short* __restrict__ Xp_t, unsigned short* __restrict__ Xp_nb)
{
    __shared__ char smem[64 * 308 * 2];    // 39424 B union
    const int vb = blockIdx.x;
    const int tid = threadIdx.x;

    if (vb < 400) {
        // ABt: tile = ((qi*5+c)*4+w)*5+nt ; n = qi*80+nt*16+(lane&15), k = c*64+w*16+(lane>>4)*4+reg
        const int tile = vb;
        const int reg = tid & 3, lane = tid >> 2;
        const int nt = tile % 5;  int r1 = tile / 5;
        const int w  = r1 % 4;    int r2 = r1 / 4;
        const int c  = r2 % 5;    const int qi = r2 / 5;
        const int n = qi*80 + nt*16 + (lane & 15);
        const int k = c*64 + w*16 + (lane >> 4)*4 + reg;
        unsigned outv = 0u;
        if (n < Nq && k < Nq) {
            float sa = 0.f, sb = 0.f;
            #pragma unroll
            for (int m = 0; m < Mq; ++m) {
                sa = fmaf(a1[n*Mq+m], a2[m*Nq+k], sa);
                sb = fmaf(b1[n*Mq+m], b2[m*Nq+k], sb);
            }
            outv = ((unsigned)f2bf(sb) << 16) | (unsigned)f2bf(sa);
        }
        ABt[tile*256 + tid] = outv;
    } else if (vb < 700) {
        // Wt bf16 [n][d][k] = (trainW1@trainW2)[n, k*64+d]
        float* sT = (float*)smem;          // [64][65]
        __shared__ float sw1[Mq];
        const int n = vb - 400;
        if (tid < Mq) sw1[tid] = w1[n*Mq + tid];
        __syncthreads();
        for (int i = tid; i < DDq; i += 256) {
            int k = i >> 6, d = i & 63;
            float s = 0.f;
            #pragma unroll
            for (int m = 0; m < Mq; ++m) s = fmaf(sw1[m], w2[m*DDq + i], s);
            sT[d*65 + k] = s;
        }
        __syncthreads();
        for (int i = tid; i < DDq; i += 256) {
            int d = i >> 6, k = i & 63;
            Wt[(size_t)n*DDq + i] = f2bf(sT[d*65 + k]);
        }
    } else if (vb < 780) {
        int e = (vb - 700) * 256 + tid;
        if (e < NP * 64) {
            int k = e >> 6, d = e & 63;
            adjWb[e] = (k < Nq) ? f2bf(adjW[k*Dq + d]) : (unsigned short)0;
        }
        if (e < NP) adjBp[e] = (e < Nq) ? adjB[e] : 0.f;
    } else {
        // X [b][d][n][t] -> Xp_t bf16 [bt][64][320] and Xp_nb bf16 [n][384][64]
        unsigned short* sT = (unsigned short*)smem;   // [64][308]
        const int bx = vb - 780;
        const int b = bx / 12, tile = bx % 12;
        const int n0 = tile * 25;
        for (int i = tid; i < 64 * 300; i += 256) {
            int d = i / 300, j = i - d * 300;
            sT[d*308 + j] = f2bf(X[(size_t)(b*64 + d)*3600 + n0*12 + j]);
        }
        __syncthreads();
        for (int wi = tid; wi < 12 * 64 * 25; wi += 256) {
            int nl = wi % 25, rem = wi / 25;
            int d = rem % 64, t = rem / 64;
            Xp_t[((size_t)(b*Tq + t)*64 + d)*NP + n0 + nl] = sT[d*308 + nl*12 + t];
        }
        if (tile == 11) {
            for (int wi = tid; wi < 12 * 64 * 20; wi += 256) {
                int e = wi % 20, rem = wi / 20;
                int d = rem % 64, t = rem / 64;
                Xp_t[((size_t)(b*Tq + t)*64 + d)*NP + 300 + e] = 0;
            }
        }
        for (int wi = tid; wi < 25 * 12 * 64; wi += 256) {
            int d = wi & 63, rem = wi >> 6;
            int t = rem % 12, nl = rem / 12;
            Xp_nb[((size_t)(n0 + nl)*BTq + b*Tq + t)*64 + d] = sT[d*308 + nl*12 + t];
        }
    }
}

// bf16 transpose: H_nb [n][384][64] -> H_t [bt][64][320] (cols>=300 zero)
__global__ void __launch_bounds__(256) ktr2(const unsigned short* __restrict__ Hnb,
                                            unsigned short* __restrict__ Ht) {
    __shared__ unsigned short sT[64 * 308];
    const int bt = blockIdx.x;
    const int tid = threadIdx.x;
    for (int i = tid; i < 300 * 64; i += 256) {
        int n = i >> 6, d = i & 63;
        sT[d*308 + n] = Hnb[((size_t)n*BTq + bt)*64 + d];
    }
    __syncthreads();
    for (int wi = tid; wi < 64 * 80; wi += 256) {
        int kq = wi % 80, d = wi / 80;
        ushort4 o;
        int k = kq * 4;
        o.x = (k+0 < Nq) ? sT[d*308 + k+0] : (unsigned short)0;
        o.y = (k+1 < Nq) ? sT[d*308 + k+1] : (unsigned short)0;
        o.z = (k+2 < Nq) ? sT[d*308 + k+2] : (unsigned short)0;
        o.w = (k+3 < Nq) ? sT[d*308 + k+3] : (unsigned short)0;
        *(ushort4*)&Ht[((size_t)bt*64 + d)*NP + k] = o;
    }
}

// Fused A-recompute + aggregation, transposed GEMM1 (P^T), tiled AB, no clamps.
// grid 1536 = (bt, n-quarter of 80); LDS = double-buffered P^T tile 2x11520 B.
__global__ void __launch_bounds__(256) kfuse(
    const float* __restrict__ te,              // [B,N,T,D] fp32 (original input)
    const unsigned short* __restrict__ adjWb,  // [320][64]
    const float* __restrict__ adjBp,           // [320]
    const unsigned* __restrict__ ABt,          // tiled pairs
    const unsigned short* __restrict__ Hb_t,   // [bt][64][320]
    unsigned short* __restrict__ Hout_nb)      // [300][384][64]
{
    __shared__ unsigned short sPl[2][80 * 72];
    const int bt = blockIdx.x >> 2, qi = blockIdx.x & 3;
    const int b = bt / Tq, t = bt - b * Tq;
    const int nbase = qi * 80;
    const int tid = threadIdx.x;
    const int w = tid >> 6, lane = tid & 63, quad = lane >> 4, l16 = lane & 15;
    const int dcol = w*16 + l16;

    bf8_t tb0[5], tb1[5];
    #pragma unroll
    for (int nt = 0; nt < 5; ++nt) {
        int n = nbase + nt*16 + l16; if (n > Nq-1) n = Nq-1;
        const float* ter = te + (((size_t)b*Nq + n)*Tq + t)*Dq;
        tb0[nt] = pack8(ld4(ter + quad*8),      ld4(ter + quad*8 + 4));
        tb1[nt] = pack8(ld4(ter + 32 + quad*8), ld4(ter + 36 + quad*8));
    }
    f4_t accO[5];
    #pragma unroll
    for (int rt = 0; rt < 5; ++rt) accO[rt] = (f4_t){0.f, 0.f, 0.f, 0.f};

    for (int c = 0; c < 5; ++c) {
        const int cbase = c * 64;
        const unsigned short* ar = adjWb + (cbase + w*16 + l16)*64;
        bf8_t ka0 = *(const bf8_t*)(ar + quad*8);
        bf8_t ka1 = *(const bf8_t*)(ar + 32 + quad*8);
        float4 bias4 = ld4(adjBp + cbase + w*16 + quad*4);
        const unsigned* abbase = ABt + ((((size_t)qi*5 + c)*4 + w)*5)*256 + lane*4;
        unsigned short* sp = sPl[c & 1];
        #pragma unroll
        for (int nt = 0; nt < 5; ++nt) {
            f4_t p = {0.f, 0.f, 0.f, 0.f};
            p = __builtin_amdgcn_mfma_f32_16x16x32_bf16(ka0, tb0[nt], p, 0, 0, 0);
            p = __builtin_amdgcn_mfma_f32_16x16x32_bf16(ka1, tb1[nt], p, 0, 0, 0);
            uint4 ab = *(const uint4*)(abbase + nt*256);
            ushort4 o4;
            {
                float sv = __sinf(p[0] + bias4.x);
                o4.x = f2bf(fmaxf(fmaf(__uint_as_float(ab.x << 16), sv,
                                       __uint_as_float(ab.x & 0xFFFF0000u)), 0.f));
            }
            {
                float sv = __sinf(p[1] + bias4.y);
                o4.y = f2bf(fmaxf(fmaf(__uint_as_float(ab.y << 16), sv,
                                       __uint_as_float(ab.y & 0xFFFF0000u)), 0.f));
            }
            {
                float sv = __sinf(p[2] + bias4.z);
                o4.z = f2bf(fmaxf(fmaf(__uint_as_float(ab.z << 16), sv,
                                       __uint_as_float(ab.z & 0xFFFF0000u)), 0.f));
            }
            {
                float sv = __sinf(p[3] + bias4.w);
                o4.w = f2bf(fmaxf(fmaf(__uint_as_float(ab.w << 16), sv,
                                       __uint_as_float(ab.w & 0xFFFF0000u)), 0.f));
            }
            *(ushort4*)&sp[(nt*16 + l16)*72 + w*16 + quad*4] = o4;
        }
        __syncthreads();
        const unsigned short* hr = Hb_t + ((size_t)bt*64 + dcol)*NP + cbase;
        bf8_t v0 = *(const bf8_t*)(hr + quad*8);
        bf8_t v1 = *(const bf8_t*)(hr + 32 + quad*8);
        #pragma unroll
        for (int rt = 0; rt < 5; ++rt) {
            bf8_t p0 = *(const bf8_t*)&sp[(rt*16 + l16)*72 + quad*8];
            bf8_t p1 = *(const bf8_t*)&sp[(rt*16 + l16)*72 + 32 + quad*8];
            accO[rt] = __builtin_amdgcn_mfma_f32_16x16x32_bf16(p0, v0, accO[rt], 0, 0, 0);
            accO[rt] = __builtin_amdgcn_mfma_f32_16x16x32_bf16(p1, v1, accO[rt], 0, 0, 0);
        }
    }
    #pragma unroll
    for (int rt = 0; rt < 5; ++rt) {
        #pragma unroll
        for (int reg = 0; reg < 4; ++reg) {
            int ng = nbase + rt*16 + quad*4 + reg;
            if (ng < Nq)
                Hout_nb[((size_t)ng*BTq + bt)*64 + dcol] = f2bf(accO[rt][reg]);
        }
    }
}

// Per-node matmul + gate. grid 1200 = (n, bt-quarter of 96). In-place safe per block.
__global__ void __launch_bounds__(256) kmm(
    const unsigned short* __restrict__ Hagg_nb,  // [n][384][64]
    const unsigned short* __restrict__ Xp_nb,    // [n][384][64]
    const unsigned short* __restrict__ Wt,       // [n][64][64]
    unsigned short* __restrict__ Hout_nb)        // [n][384][64]
{
    const int n = blockIdx.x >> 2, qi = blockIdx.x & 3;
    const int bt0 = qi * 96;
    const int tid = threadIdx.x;
    const int w = tid >> 6, lane = tid & 63, quad = lane >> 4, l16 = lane & 15;
    const int dcol = w*16 + l16;
    const unsigned short* wn = Wt + (size_t)n * DDq + dcol*64;
    bf8_t v0 = *(const bf8_t*)(wn + quad*8);
    bf8_t v1 = *(const bf8_t*)(wn + 32 + quad*8);
    f4_t acc[6];
    #pragma unroll
    for (int rt = 0; rt < 6; ++rt) acc[rt] = (f4_t){0.f, 0.f, 0.f, 0.f};
    #pragma unroll
    for (int rt = 0; rt < 6; ++rt) {
        int r = bt0 + rt*16 + l16;
        const unsigned short* row = Hagg_nb + ((size_t)n*BTq + r)*64;
        bf8_t a0 = *(const bf8_t*)(row + quad*8);
        bf8_t a1 = *(const bf8_t*)(row + 32 + quad*8);
        acc[rt] = __builtin_amdgcn_mfma_f32_16x16x32_bf16(a0, v0, acc[rt], 0, 0, 0);
        acc[rt] = __builtin_amdgcn_mfma_f32_16x16x32_bf16(a1, v1, acc[rt], 0, 0, 0);
    }
    __syncthreads();
    #pragma unroll
    for (int rt = 0; rt < 6; ++rt) {
        #pragma unroll
        for (int reg = 0; reg < 4; ++reg) {
            int r = bt0 + rt*16 + quad*4 + reg;
            size_t idx = ((size_t)n*BTq + r)*64 + dcol;
            float xp = bf2f(Xp_nb[idx]);
            Hout_nb[idx] = f2bf(gatef(xp + acc[rt][reg]));
        }
    }
}

// GCN epilogue: out[b,d,n,t] = gcnB[d] + [Xp|H1|H2]@gcnW[d,:]. grid 608 = (b, n-tile 16).
__global__ void __launch_bounds__(256) kgcn(
    const unsigned short* __restrict__ Xp_nb, const unsigned short* __restrict__ H1_nb,
    const unsigned short* __restrict__ H2_nb, const float* __restrict__ gcnW,
    const float* __restrict__ gcnB, float* __restrict__ out)
{
    const int b = blockIdx.x / 19, tile = blockIdx.x % 19;
    const int n0 = tile * 16;
    const int rows = (tile == 18) ? 144 : 192;
    const int tid = threadIdx.x;
    const int w = tid >> 6, lane = tid & 63, quad = lane >> 4, l16 = lane & 15;
    const int dcol = w*16 + l16;
    const float bias = gcnB[dcol];
    f4_t acc[12];
    #pragma unroll
    for (int rt = 0; rt < 12; ++rt) acc[rt] = (f4_t){0.f, 0.f, 0.f, 0.f};
    const unsigned short* bufs[3] = {Xp_nb, H1_nb, H2_nb};
    #pragma unroll
    for (int c = 0; c < 3; ++c) {
        const unsigned short* buf = bufs[c];
        const float* gwr = gcnW + (size_t)dcol*Fq + c*Dq;
        bf8_t v0 = pack8(ld4(gwr + quad*8),      ld4(gwr + quad*8 + 4));
        bf8_t v1 = pack8(ld4(gwr + 32 + quad*8), ld4(gwr + 36 + quad*8));
        #pragma unroll
        for (int rt = 0; rt < 12; ++rt) {
            int r = rt*16 + l16;
            int nl = r / 12, t = r - nl*12;
            int n = n0 + nl; if (n > Nq-1) n = Nq-1;
            const unsigned short* row = buf + ((size_t)n*BTq + b*Tq + t)*64;
            bf8_t a0 = *(const bf8_t*)(row + quad*8);
            bf8_t a1 = *(const bf8_t*)(row + 32 + quad*8);
            acc[rt] = __builtin_amdgcn_mfma_f32_16x16x32_bf16(a0, v0, acc[rt], 0, 0, 0);
            acc[rt] = __builtin_amdgcn_mfma_f32_16x16x32_bf16(a1, v1, acc[rt], 0, 0, 0);
        }
    }
    float* outd = out + (size_t)(b*Dq + dcol)*3600 + n0*12;
    #pragma unroll
    for (int rt = 0; rt < 12; ++rt) {
        if (rt*16 < rows) {
            int r0 = rt*16 + quad*4;
            float4 o = make_float4(acc[rt][0] + bias, acc[rt][1] + bias,
                                   acc[rt][2] + bias, acc[rt][3] + bias);
            *(float4*)&outd[r0] = o;
        }
    }
}

extern "C" void kernel_launch(void* const* d_in, const int* in_sizes, int n_in,
                              void* d_out, int out_size, void* d_ws, size_t ws_size,
                              hipStream_t stream) {
    (void)in_sizes; (void)n_in; (void)out_size; (void)ws_size;
    const float* X    = (const float*)d_in[0];
    const float* te   = (const float*)d_in[1];
    const float* adjW = (const float*)d_in[2];
    const float* adjB = (const float*)d_in[3];
    const float* w1   = (const float*)d_in[4];
    const float* w2   = (const float*)d_in[5];
    const float* a1   = (const float*)d_in[6];
    const float* a2   = (const float*)d_in[7];
    const float* b1   = (const float*)d_in[8];
    const float* b2   = (const float*)d_in[9];
    const float* gW   = (const float*)d_in[10];
    const float* gB   = (const float*)d_in[11];
    float* out = (float*)d_out;

    char* ws = (char*)d_ws;
    unsigned*       ABt    = (unsigned*)      (ws);               //    409,600
    unsigned short* adjWb  = (unsigned short*)(ws + 409600);      //  +  40,960 =    450,560
    float*          adjBp  = (float*)         (ws + 450560);      //  +   1,280 =    451,840
    unsigned short* Wt     = (unsigned short*)(ws + 451840);      //  +2,457,600 =  2,909,440
    unsigned short* Xp_t   = (unsigned short*)(ws + 2909440);     // +15,728,640 = 18,638,080
    unsigned short* Xp_nb  = (unsigned short*)(ws + 18638080);    // +14,745,600 = 33,383,680
    unsigned short* Hagg   = (unsigned short*)(ws + 33383680);    // +14,745,600 = 48,129,280
    unsigned short* H1_nb  = (unsigned short*)(ws + 48129280);    // +14,745,600 = 62,874,880
    unsigned short* H1_t   = (unsigned short*)(ws + 62874880);    // +15,728,640 = 78,603,520 B

    hipLaunchKernelGGL(kprep_all, dim3(1164), dim3(256), 0, stream,
                       a1, a2, b1, b2, w1, w2, adjW, adjB, X,
                       ABt, Wt, adjWb, adjBp, Xp_t, Xp_nb);
    // hop 1
    hipLaunchKernelGGL(kfuse, dim3(1536), dim3(256), 0, stream, te, adjWb, adjBp, ABt, Xp_t, Hagg);
    hipLaunchKernelGGL(kmm,   dim3(1200), dim3(256), 0, stream, Hagg, Xp_nb, Wt, H1_nb);
    hipLaunchKernelGGL(ktr2,  dim3(384),  dim3(256), 0, stream, H1_nb, H1_t);
    // hop 2
    hipLaunchKernelGGL(kfuse, dim3(1536), dim3(256), 0, stream, te, adjWb, adjBp, ABt, H1_t, Hagg);
    hipLaunchKernelGGL(kmm,   dim3(1200), dim3(256), 0, stream, Hagg, Xp_nb, Wt, Hagg); // in-place -> H2
    // gcn epilogue
    hipLaunchKernelGGL(kgcn,  dim3(608), dim3(256), 0, stream, Xp_nb, H1_nb, Hagg, gW, gB, out);
}